// Round 6
// baseline (567.687 us; speedup 1.0000x reference)
//
#include <hip/hip_runtime.h>
#include <math.h>

// ScatterNet — round 12:
// - k_gatagg3: 64-row slices (768 -> 1536 blocks, 6 blocks/CU, 75% occ target),
//   head-shared panel kept (L1 reuse), one 16-row group per wave (no mt loop),
//   LDS 12.6KB. Tests the latency-bound hypothesis from round-5 postmortem.
// - everything else as round 11.

typedef __bf16 bf16;
typedef __bf16 bf16x8 __attribute__((ext_vector_type(8)));
typedef __bf16 bf16x4 __attribute__((ext_vector_type(4)));
typedef float f32x4 __attribute__((ext_vector_type(4)));

__device__ __forceinline__ float bf2f(bf16 x) { return (float)x; }
__device__ __forceinline__ bf16 f2bf(float x) { return (bf16)x; }

// monotone float<->uint for atomicMax on signed floats
__device__ __forceinline__ unsigned encf(float f) {
    unsigned u = __float_as_uint(f);
    return (u & 0x80000000u) ? ~u : (u | 0x80000000u);
}
__device__ __forceinline__ float decf(unsigned u) {
    return (u & 0x80000000u) ? __uint_as_float(u & 0x7fffffffu)
                             : __uint_as_float(~u);
}

// ---------------------------------------------------------------------------
// Weight prep: fp32 [R][C] -> bf16; trans=1: [C][R], trans=0: [R][C] copy.
// ---------------------------------------------------------------------------
struct PrepEnt { const float* src; long dofs; int R; int C; int tstart; int trans; };
struct PrepTab { PrepEnt e[13]; };

__global__ __launch_bounds__(256) void k_prep(PrepTab tab, bf16* __restrict__ dst)
{
    __shared__ float tile[32][33];
    const int tid = blockIdx.x;
    int k = 0;
    #pragma unroll
    for (int q = 1; q < 13; ++q) if (tid >= tab.e[q].tstart) k = q;
    PrepEnt E = tab.e[k];
    const int local = tid - E.tstart;
    const int cT = E.C >> 5;
    const int tr = local / cT, tc = local - tr * cT;
    const int r0 = tr << 5, c0 = tc << 5;
    const int t = threadIdx.x;
    {
        int r = t >> 3, cq = (t & 7) * 4;
        *(float4*)&tile[r][cq] = *(const float4*)(E.src + (long)(r0 + r) * E.C + c0 + cq);
    }
    __syncthreads();
    if (E.trans) {
        int c = t >> 3, rq = (t & 7) * 4;
        bf16x4 o;
        o[0] = f2bf(tile[rq + 0][c]); o[1] = f2bf(tile[rq + 1][c]);
        o[2] = f2bf(tile[rq + 2][c]); o[3] = f2bf(tile[rq + 3][c]);
        *(bf16x4*)(dst + E.dofs + (long)(c0 + c) * E.R + r0 + rq) = o;
    } else {
        int r = t >> 3, cq = (t & 7) * 4;
        bf16x4 o;
        o[0] = f2bf(tile[r][cq + 0]); o[1] = f2bf(tile[r][cq + 1]);
        o[2] = f2bf(tile[r][cq + 2]); o[3] = f2bf(tile[r][cq + 3]);
        *(bf16x4*)(dst + E.dofs + (long)(r0 + r) * E.C + c0 + cq) = o;
    }
}

// ---------------------------------------------------------------------------
// 64x64 MFMA GEMM core. D: row = m0 + wv*16 + kq*4 + i, col = n0 + nt*16 + lr.
// ---------------------------------------------------------------------------
__device__ __forceinline__ void gemm_bt_mn(const bf16* __restrict__ A, int lda,
                                           const bf16* __restrict__ BT, int ldb,
                                           int K, int m0, int n0, f32x4 acc[4])
{
    __shared__ bf16 As[64][40];
    __shared__ bf16 Bs[64][40];
    const int t = threadIdx.x;
    const int lane = t & 63, wv = t >> 6, lr = lane & 15, kq = lane >> 4;
    const int arow = t >> 2, acol = (t & 3) * 8;
    for (int k0 = 0; k0 < K; k0 += 32) {
        __syncthreads();
        *(uint4*)&As[arow][acol] = *(const uint4*)(A + (long)(m0 + arow) * lda + k0 + acol);
        *(uint4*)&Bs[arow][acol] = *(const uint4*)(BT + (long)(n0 + arow) * ldb + k0 + acol);
        __syncthreads();
        bf16x8 af = *(const bf16x8*)&As[wv * 16 + lr][kq * 8];
        #pragma unroll
        for (int nt = 0; nt < 4; ++nt) {
            bf16x8 bfr = *(const bf16x8*)&Bs[nt * 16 + lr][kq * 8];
            acc[nt] = __builtin_amdgcn_mfma_f32_16x16x32_bf16(af, bfr, acc[nt], 0, 0, 0);
        }
    }
}

__device__ __forceinline__ void gemm_bt(const bf16* __restrict__ A, int lda,
                                        const bf16* __restrict__ BT, int ldb,
                                        int K, f32x4 acc[4])
{
    gemm_bt_mn(A, lda, BT, ldb, K, blockIdx.y * 64, blockIdx.x * 64, acc);
}

// ---------------------------------------------------------------------------
// 128x128 MFMA GEMM core (BK=32), used by kvq / eff1.
// ---------------------------------------------------------------------------
__device__ __forceinline__ void gemm128_core(const bf16* __restrict__ A, int lda,
                                             const bf16* __restrict__ BT, int ldb,
                                             int m0, int n0, int K, f32x4 acc[2][8])
{
    __shared__ bf16 As[128][40];
    __shared__ bf16 Bs[128][40];
    const int t = threadIdx.x;
    const int lane = t & 63, wv = t >> 6, lr = lane & 15, kq = lane >> 4;
    const int srow = t >> 1, scol = (t & 1) * 16;
    for (int k0 = 0; k0 < K; k0 += 32) {
        __syncthreads();
        {
            const bf16* ap = A + (long)(m0 + srow) * lda + k0 + scol;
            *(uint4*)&As[srow][scol] = *(const uint4*)ap;
            *(uint4*)&As[srow][scol + 8] = *(const uint4*)(ap + 8);
            const bf16* bp = BT + (long)(n0 + srow) * ldb + k0 + scol;
            *(uint4*)&Bs[srow][scol] = *(const uint4*)bp;
            *(uint4*)&Bs[srow][scol + 8] = *(const uint4*)(bp + 8);
        }
        __syncthreads();
        bf16x8 af[2];
        af[0] = *(const bf16x8*)&As[wv * 32 + lr][kq * 8];
        af[1] = *(const bf16x8*)&As[wv * 32 + 16 + lr][kq * 8];
        #pragma unroll
        for (int nt = 0; nt < 8; ++nt) {
            bf16x8 bfr = *(const bf16x8*)&Bs[nt * 16 + lr][kq * 8];
            acc[0][nt] = __builtin_amdgcn_mfma_f32_16x16x32_bf16(af[0], bfr, acc[0][nt], 0, 0, 0);
            acc[1][nt] = __builtin_amdgcn_mfma_f32_16x16x32_bf16(af[1], bfr, acc[1][nt], 0, 0, 0);
        }
    }
}

// eff1 GEMM (relu)
__global__ __launch_bounds__(256) void k_gemm128_bf16(
    const bf16* __restrict__ A, int lda,
    const bf16* __restrict__ BT, int ldb,
    bf16* __restrict__ out, int ldo, int K, int relu)
{
    f32x4 acc[2][8] = {};
    const int m0 = blockIdx.y * 128, n0 = blockIdx.x * 128;
    gemm128_core(A, lda, BT, ldb, m0, n0, K, acc);
    const int lane = threadIdx.x & 63, wv = threadIdx.x >> 6;
    const int lr = lane & 15, kq = lane >> 4;
    #pragma unroll
    for (int mt = 0; mt < 2; ++mt) {
        #pragma unroll
        for (int nt = 0; nt < 8; ++nt) {
            int col = n0 + nt * 16 + lr;
            #pragma unroll
            for (int i = 0; i < 4; ++i) {
                int row = m0 + wv * 32 + mt * 16 + kq * 4 + i;
                float v = acc[mt][nt][i];
                if (relu) v = fmaxf(v, 0.f);
                out[(long)row * ldo + col] = f2bf(v);
            }
        }
    }
}

// combined KV + q projection (one launch), XCD-chunked swizzle
__global__ __launch_bounds__(256) void k_kvq(
    const bf16* __restrict__ hln, const bf16* __restrict__ WqkvT,
    bf16* __restrict__ kv, bf16* __restrict__ q)
{
    const int wg = (blockIdx.x & 7) * 272 + (blockIdx.x >> 3);
    const bf16* A; const bf16* BT; bf16* out;
    int lda, ldo, m0, n0;
    if (wg < 2048) {           // KV: 65536 rows x 512 cols
        A = hln; lda = 256; BT = WqkvT + 65536;
        m0 = (wg >> 2) * 128; n0 = (wg & 3) * 128;
        out = kv; ldo = 512;
    } else {                    // q: 8192 rows (stride-8 rows of hln) x 256 cols
        int t2 = wg - 2048;
        A = hln; lda = 2048; BT = WqkvT;
        m0 = (t2 >> 1) * 128; n0 = (t2 & 1) * 128;
        out = q; ldo = 256;
    }
    f32x4 acc[2][8] = {};
    gemm128_core(A, lda, BT, 256, m0, n0, 256, acc);
    const int lane = threadIdx.x & 63, wv = threadIdx.x >> 6;
    const int lr = lane & 15, kq = lane >> 4;
    #pragma unroll
    for (int mt = 0; mt < 2; ++mt) {
        #pragma unroll
        for (int nt = 0; nt < 8; ++nt) {
            int col = n0 + nt * 16 + lr;
            #pragma unroll
            for (int i = 0; i < 4; ++i) {
                int row = m0 + wv * 32 + mt * 16 + kq * 4 + i;
                out[(long)row * ldo + col] = f2bf(acc[mt][nt][i]);
            }
        }
    }
}

// Wc^T = Wk @ Wq^T (bf16), per cls head. 32 blocks.
__global__ __launch_bounds__(256) void k_wcomb(bf16* __restrict__ wb)
{
    const int bid = blockIdx.x;
    const int head = bid >> 4, r = bid & 15;
    const bf16* A  = wb + 1179648 + head * 131072;   // Wk plain
    const bf16* BT = wb + 1114112 + head * 131072;   // Wq plain
    bf16* out = wb + 1376256 + head * 65536;         // WcT
    const int m0 = (r >> 2) * 64, n0 = (r & 3) * 64;
    f32x4 acc[4] = {};
    gemm_bt_mn(A, 256, BT, 256, 256, m0, n0, acc);
    const int lane = threadIdx.x & 63, wv = threadIdx.x >> 6;
    const int lr = lane & 15, kq = lane >> 4;
    #pragma unroll
    for (int nt = 0; nt < 4; ++nt) {
        int col = n0 + nt * 16 + lr;
        #pragma unroll
        for (int i = 0; i < 4; ++i) {
            int row = m0 + wv * 16 + kq * 4 + i;
            out[(long)row * 256 + col] = f2bf(acc[nt][i]);
        }
    }
}

// y = x @ Wc (main + det combined), XCD-chunked swizzle
__global__ __launch_bounds__(256) void k_y(
    const bf16* __restrict__ xm, const bf16* __restrict__ WcT0, bf16* __restrict__ ym,
    const bf16* __restrict__ xd, const bf16* __restrict__ WcT1, bf16* __restrict__ yd)
{
    const int wg = (blockIdx.x & 7) * 192 + (blockIdx.x >> 3);
    int by = wg >> 2;
    const int bx = wg & 3;
    const bf16 *A, *BT; bf16* out;
    if (by < 256) { A = xm; BT = WcT0; out = ym; }
    else          { by -= 256; A = xd; BT = WcT1; out = yd; }
    f32x4 acc[4] = {};
    const int m0 = by * 64, n0 = bx * 64;
    gemm_bt_mn(A, 256, BT, 256, 256, m0, n0, acc);
    const int lane = threadIdx.x & 63, wv = threadIdx.x >> 6;
    const int lr = lane & 15, kq = lane >> 4;
    #pragma unroll
    for (int nt = 0; nt < 4; ++nt) {
        int col = n0 + nt * 16 + lr;
        #pragma unroll
        for (int i = 0; i < 4; ++i) {
            int row = m0 + wv * 16 + kq * 4 + i;
            out[(long)row * 256 + col] = f2bf(acc[nt][i]);
        }
    }
}

// logits = y @ x^T, sigmoid(/16)*adj epilogue. BK=64 core, XCD swizzle.
__global__ __launch_bounds__(256) void k_logits(
    const bf16* __restrict__ ym, const bf16* __restrict__ xm,
    const bf16* __restrict__ yd, const bf16* __restrict__ xd,
    const unsigned long long* __restrict__ adjmM,
    const unsigned long long* __restrict__ adjmD,
    float* __restrict__ out, float* __restrict__ asso)
{
    const int wg = (blockIdx.x & 7) * 160 + (blockIdx.x >> 3);
    const bf16 *A, *BT; float* ob; const unsigned long long* adjm;
    int ldo, nN, nC, flags, m0, n0, z;
    if (wg < 1024) {
        z = wg >> 6; int r = wg & 63;
        m0 = (r >> 3) * 128; n0 = (r & 7) * 128;
        A = ym + (long)z * 262144; BT = xm + (long)z * 262144;
        ob = out + (long)z * 1048576; ldo = 1024;
        adjm = adjmM; nN = 1024; nC = 16; flags = 1;
    } else {
        int t2 = wg - 1024;
        z = t2 >> 4; int r = t2 & 15;
        m0 = (r >> 2) * 128; n0 = (r & 3) * 128;
        A = yd + (long)z * 131072; BT = xd + (long)z * 131072;
        ob = out + 16777216 + (long)z * 262144; ldo = 512;
        adjm = adjmD; nN = 512; nC = 8; flags = 2;
    }
    const int t = threadIdx.x;
    const int lane = t & 63, wv = t >> 6, lr = lane & 15, kq = lane >> 4;
    f32x4 acc[2][8] = {};
    {
        __shared__ bf16 As[128][72];
        __shared__ bf16 Bs[128][72];
        const int srow4 = t >> 3, scol8 = (t & 7) * 8;
        for (int k0 = 0; k0 < 256; k0 += 64) {
            __syncthreads();
            #pragma unroll
            for (int p = 0; p < 4; ++p) {
                int row = p * 32 + srow4;
                *(uint4*)&As[row][scol8] = *(const uint4*)(A + (long)(m0 + row) * 256 + k0 + scol8);
                *(uint4*)&Bs[row][scol8] = *(const uint4*)(BT + (long)(n0 + row) * 256 + k0 + scol8);
            }
            __syncthreads();
            #pragma unroll
            for (int ks = 0; ks < 64; ks += 32) {
                bf16x8 af[2];
                af[0] = *(const bf16x8*)&As[wv * 32 + lr][kq * 8 + ks];
                af[1] = *(const bf16x8*)&As[wv * 32 + 16 + lr][kq * 8 + ks];
                #pragma unroll
                for (int nt = 0; nt < 8; ++nt) {
                    bf16x8 bfr = *(const bf16x8*)&Bs[nt * 16 + lr][kq * 8 + ks];
                    acc[0][nt] = __builtin_amdgcn_mfma_f32_16x16x32_bf16(af[0], bfr, acc[0][nt], 0, 0, 0);
                    acc[1][nt] = __builtin_amdgcn_mfma_f32_16x16x32_bf16(af[1], bfr, acc[1][nt], 0, 0, 0);
                }
            }
        }
    }
    #pragma unroll
    for (int mt = 0; mt < 2; ++mt) {
        #pragma unroll
        for (int i = 0; i < 4; ++i) {
            int row = m0 + wv * 32 + mt * 16 + kq * 4 + i;
            unsigned long long w0 = adjm[((long)z * nN + row) * nC + (n0 >> 6)];
            unsigned long long w1 = adjm[((long)z * nN + row) * nC + (n0 >> 6) + 1];
            #pragma unroll
            for (int nt = 0; nt < 8; ++nt) {
                int col = n0 + nt * 16 + lr;
                int bp = nt * 16 + lr;
                bool adj = (bp < 64) ? ((w0 >> bp) & 1ull) : ((w1 >> (bp - 64)) & 1ull);
                if ((flags & 2) && row == col) adj = false;
                float v = 0.f;
                if (adj) v = 1.f / (1.f + __expf(-acc[mt][nt][i] * 0.0625f));
                ob[(long)row * ldo + col] = v;
                if ((flags & 1) && row < 512 && col >= 512)
                    asso[(long)z * 262144 + (long)row * 512 + (col - 512)] = v;
            }
        }
    }
}

// predicted = tr_emb0 + 0.9*(x2_0 + ff2_out); scattered to feat0[b*1024+m]
__global__ __launch_bounds__(256) void k_gemm_pred(
    const bf16* __restrict__ A, int lda,
    const bf16* __restrict__ BT, int ldb,
    const float* __restrict__ res1, const float* __restrict__ res2,
    float* __restrict__ outf, bf16* __restrict__ outb, int K)
{
    f32x4 acc[4] = {};
    gemm_bt(A, lda, BT, ldb, K, acc);
    const int lane = threadIdx.x & 63, wv = threadIdx.x >> 6;
    const int lr = lane & 15, kq = lane >> 4;
    const int m0 = blockIdx.y * 64, n0 = blockIdx.x * 64;
    #pragma unroll
    for (int nt = 0; nt < 4; ++nt) {
        int col = n0 + nt * 16 + lr;
        #pragma unroll
        for (int i = 0; i < 4; ++i) {
            int row = m0 + wv * 16 + kq * 4 + i;     // b*512 + m
            float v = res1[(long)row * 256 + col]
                    + 0.9f * (res2[(long)row * 256 + col] + acc[nt][i]);
            long drow = (long)row + ((row >> 9) << 9);   // b*1024 + m
            long o = drow * 256 + col;
            outf[o] = v;
            outb[o] = f2bf(v);
        }
    }
}

// ---------------------------------------------------------------------------
// fused feat MLP + LayerNorm epilogue (track rows). 64 rows x 256 cols/block.
// ---------------------------------------------------------------------------
__global__ __launch_bounds__(256) void k_featgemm(
    const float* __restrict__ tracks, const float* __restrict__ dets,
    const float* __restrict__ W1, const float* __restrict__ b1,
    const bf16* __restrict__ W2T, const float* __restrict__ b2,
    bf16* __restrict__ hln, float* __restrict__ emb_r0_f,
    float* __restrict__ feat0_f, bf16* __restrict__ feat0_b,
    bf16* __restrict__ demb_b)
{
    __shared__ float xr[64][4];
    __shared__ float w1s[4][256];
    __shared__ float b1s[256];
    __shared__ bf16 As[64][40];
    __shared__ bf16 Bs[256][40];
    const int t = threadIdx.x;
    const int m0 = blockIdx.x * 64;
    if (t < 64) {
        int gr = m0 + t;
        const float* sp = (gr < 65536) ? (tracks + (long)gr * 4)
                                       : (dets + (long)(gr - 65536) * 4);
        *(float4*)&xr[t][0] = *(const float4*)sp;
    }
    w1s[0][t] = W1[t];       w1s[1][t] = W1[256 + t];
    w1s[2][t] = W1[512 + t]; w1s[3][t] = W1[768 + t];
    b1s[t] = b1[t];
    const int arow = t >> 2, acol = (t & 3) * 8;
    const int lane = t & 63, wv = t >> 6, lr = lane & 15, kq = lane >> 4;
    f32x4 acc[16] = {};
    __syncthreads();
    for (int k0 = 0; k0 < 256; k0 += 32) {
        __syncthreads();
        #pragma unroll
        for (int j = 0; j < 8; ++j) {
            int c = k0 + acol + j;
            float v = fmaf(xr[arow][0], w1s[0][c],
                      fmaf(xr[arow][1], w1s[1][c],
                      fmaf(xr[arow][2], w1s[2][c],
                      fmaf(xr[arow][3], w1s[3][c], b1s[c]))));
            v = v > 0.f ? v : (__expf(v) - 1.f);
            As[arow][acol + j] = f2bf(v);
        }
        #pragma unroll
        for (int rr = 0; rr < 4; ++rr) {
            int n = rr * 64 + (t >> 2);
            *(uint4*)&Bs[n][acol] = *(const uint4*)(W2T + (long)n * 256 + k0 + acol);
        }
        __syncthreads();
        bf16x8 af = *(const bf16x8*)&As[wv * 16 + lr][kq * 8];
        #pragma unroll
        for (int nt = 0; nt < 16; ++nt) {
            bf16x8 bfr = *(const bf16x8*)&Bs[nt * 16 + lr][kq * 8];
            acc[nt] = __builtin_amdgcn_mfma_f32_16x16x32_bf16(af, bfr, acc[nt], 0, 0, 0);
        }
    }
    if (m0 < 65536) {
        #pragma unroll
        for (int nt = 0; nt < 16; ++nt) {
            int col = nt * 16 + lr;
            float bv = b2[col];
            #pragma unroll
            for (int i = 0; i < 4; ++i) {
                int gr = m0 + wv * 16 + kq * 4 + i;
                float v = acc[nt][i] + bv;
                if ((gr & 7) == 0) emb_r0_f[(long)(gr >> 3) * 256 + col] = v;
                acc[nt][i] = bf2f(f2bf(v));   // bit-match old bf16 emb path
            }
        }
        float mean[4], rstd[4];
        #pragma unroll
        for (int i = 0; i < 4; ++i) {
            float s1 = 0.f, s2 = 0.f;
            #pragma unroll
            for (int nt = 0; nt < 16; ++nt) {
                float v = acc[nt][i];
                s1 += v; s2 += v * v;
            }
            #pragma unroll
            for (int o = 1; o < 16; o <<= 1) {
                s1 += __shfl_xor(s1, o, 64);
                s2 += __shfl_xor(s2, o, 64);
            }
            float mu = s1 * (1.f / 256.f);
            mean[i] = mu;
            rstd[i] = rsqrtf(fmaxf(s2 * (1.f / 256.f) - mu * mu, 0.f) + 1e-5f);
        }
        #pragma unroll
        for (int nt = 0; nt < 16; ++nt) {
            int col = nt * 16 + lr;
            #pragma unroll
            for (int i = 0; i < 4; ++i) {
                int gr = m0 + wv * 16 + kq * 4 + i;
                hln[(long)gr * 256 + col] = f2bf((acc[nt][i] - mean[i]) * rstd[i]);
            }
        }
    } else {
        #pragma unroll
        for (int nt = 0; nt < 16; ++nt) {
            int col = nt * 16 + lr;
            float bv = b2[col];
            #pragma unroll
            for (int i = 0; i < 4; ++i) {
                int gr = m0 + wv * 16 + kq * 4 + i;
                float v = acc[nt][i] + bv;
                int dr = gr - 65536;
                long drow = ((long)(dr >> 9) << 10) + 512 + (dr & 511);
                feat0_f[drow * 256 + col] = v;
                feat0_b[drow * 256 + col] = f2bf(v);
                demb_b[(long)dr * 256 + col] = f2bf(v);
            }
        }
    }
}

// adjacency bitmask: LDS-staged nodes, 32 rows per block.
__global__ __launch_bounds__(256) void k_adjmask(
    const float4* __restrict__ nodes,
    unsigned long long* __restrict__ adjm_main,
    unsigned long long* __restrict__ adjm_det)
{
    __shared__ float4 nds[1024];
    int bid = blockIdx.x;
    int nN, b, i0, nodeOfs;
    unsigned long long* adjm;
    if (bid < 512) { nN = 1024; b = bid >> 5; i0 = (bid & 31) << 5; nodeOfs = 0; adjm = adjm_main; }
    else { int b2 = bid - 512; nN = 512; b = b2 >> 4; i0 = (b2 & 15) << 5; nodeOfs = 512; adjm = adjm_det; }
    const float4* nb = nodes + b * 1024 + nodeOfs;
    const int t = threadIdx.x;
    for (int j = t; j < nN; j += 256) nds[j] = nb[j];
    __syncthreads();
    const int w = t >> 6, l = t & 63;
    const int nC = nN >> 6;
    for (int ii = 0; ii < 8; ++ii) {
        int i = i0 + w * 8 + ii;
        float4 ni = nds[i];
        for (int c = 0; c < nC; ++c) {
            float4 nj = nds[c * 64 + l];
            float dx = ni.x - nj.x, dy = ni.y - nj.y;
            bool adj = (dx * dx + dy * dy < 4.f) && (ni.z + nj.z < 1.f);
            unsigned long long mask = __ballot(adj);
            if (l == 0) adjm[(long)(b * nN + i) * nC + c] = mask;
        }
    }
}

// Wo-residual + LayerNorm, wide-N: 64 rows x 256 cols/block.
__global__ __launch_bounds__(256) void k_addres_ln(
    const bf16* __restrict__ A, const bf16* __restrict__ BT,
    const float* __restrict__ res1,
    float* __restrict__ x2out, bf16* __restrict__ h2)
{
    __shared__ bf16 As[64][40];
    __shared__ bf16 Bs[256][40];
    const int t = threadIdx.x;
    const int m0 = blockIdx.x * 64;
    const int arow = t >> 2, acol = (t & 3) * 8;
    const int lane = t & 63, wv = t >> 6, lr = lane & 15, kq = lane >> 4;
    f32x4 acc[16] = {};
    for (int k0 = 0; k0 < 256; k0 += 32) {
        __syncthreads();
        *(uint4*)&As[arow][acol] = *(const uint4*)(A + (long)(m0 + arow) * 256 + k0 + acol);
        #pragma unroll
        for (int rr = 0; rr < 4; ++rr) {
            int n = rr * 64 + (t >> 2);
            *(uint4*)&Bs[n][acol] = *(const uint4*)(BT + (long)n * 256 + k0 + acol);
        }
        __syncthreads();
        bf16x8 af = *(const bf16x8*)&As[wv * 16 + lr][kq * 8];
        #pragma unroll
        for (int nt = 0; nt < 16; ++nt) {
            bf16x8 bfr = *(const bf16x8*)&Bs[nt * 16 + lr][kq * 8];
            acc[nt] = __builtin_amdgcn_mfma_f32_16x16x32_bf16(af, bfr, acc[nt], 0, 0, 0);
        }
    }
    float mean[4], rstd[4];
    #pragma unroll
    for (int i = 0; i < 4; ++i) {
        int row = m0 + wv * 16 + kq * 4 + i;
        float s1 = 0.f, s2 = 0.f;
        #pragma unroll
        for (int nt = 0; nt < 16; ++nt) {
            float v = res1[(long)row * 256 + nt * 16 + lr] + acc[nt][i];
            acc[nt][i] = v;
            s1 += v; s2 += v * v;
        }
        #pragma unroll
        for (int o = 1; o < 16; o <<= 1) {
            s1 += __shfl_xor(s1, o, 64);
            s2 += __shfl_xor(s2, o, 64);
        }
        float mu = s1 * (1.f / 256.f);
        mean[i] = mu;
        rstd[i] = rsqrtf(fmaxf(s2 * (1.f / 256.f) - mu * mu, 0.f) + 1e-5f);
    }
    #pragma unroll
    for (int nt = 0; nt < 16; ++nt) {
        int col = nt * 16 + lr;
        #pragma unroll
        for (int i = 0; i < 4; ++i) {
            int row = m0 + wv * 16 + kq * 4 + i;
            float v = acc[nt][i];
            x2out[(long)row * 256 + col] = v;
            h2[(long)row * 256 + col] = f2bf((v - mean[i]) * rstd[i]);
        }
    }
}

// encoder attention, r=0 row only. kv layout: [row][512]
__global__ __launch_bounds__(256) void k_attn(
    const bf16* __restrict__ q, const bf16* __restrict__ kv,
    bf16* __restrict__ o0)
{
    const long t = blockIdx.x;
    const int h = threadIdx.x >> 6;
    const int lane = threadIdx.x & 63;
    const int s = lane >> 3;
    const int dg = lane & 7;
    const bf16* qp = q + t * 256 + h * 64 + dg * 8;
    const bf16* kp = kv + (t * 8 + s) * 512 + h * 64 + dg * 8;
    float p = 0.f;
    #pragma unroll
    for (int e = 0; e < 8; ++e) p += bf2f(qp[e]) * bf2f(kp[e]);
    p += __shfl_xor(p, 1, 64);
    p += __shfl_xor(p, 2, 64);
    p += __shfl_xor(p, 4, 64);
    float sc = p * 0.125f;
    float w[8];
    float mx = -1e30f;
    #pragma unroll
    for (int s2 = 0; s2 < 8; ++s2) { w[s2] = __shfl(sc, s2 * 8, 64); mx = fmaxf(mx, w[s2]); }
    float sum = 0.f;
    #pragma unroll
    for (int s2 = 0; s2 < 8; ++s2) { w[s2] = __expf(w[s2] - mx); sum += w[s2]; }
    float rs = 1.f / sum;
    float acc = 0.f;
    const bf16* vp = kv + (t * 8) * 512 + 256 + h * 64 + lane;
    #pragma unroll
    for (int s2 = 0; s2 < 8; ++s2) acc += w[s2] * bf2f(vp[(long)s2 * 512]);
    o0[t * 256 + h * 64 + lane] = f2bf(acc * rs);
}

__global__ __launch_bounds__(256) void k_nodes(
    const float* __restrict__ tracks, const float* __restrict__ dets,
    const int* __restrict__ tm, const int* __restrict__ dm,
    float4* __restrict__ nodes, unsigned* __restrict__ maxd_all)
{
    int idx = blockIdx.x * 256 + threadIdx.x;
    if (blockIdx.x == 0) maxd_all[threadIdx.x] = 0x007fffffu;   // enc(-inf), 4 layers x 64
    int b = idx >> 10;
    int i = idx & 1023;
    float x, y;
    int valid;
    if (i < 512) {
        long o = (long)(b * 512 + i) * 32;
        x = tracks[o]; y = tracks[o + 1];
        valid = (i < tm[b]) ? 1 : 0;
    } else {
        int n = i - 512;
        long o = (long)(b * 512 + n) * 4;
        x = dets[o]; y = dets[o + 1];
        valid = (n < dm[b]) ? 1 : 0;
    }
    nodes[idx] = make_float4(x, y, valid ? 0.f : 1e9f, 0.f);
}

// ---------------------------------------------------------------------------
// combined main+det GAT projection (transposed out) with FUSED src/dst dots.
// 1D grid, logical wg: head = wg&3, bx = wg>>2 (4 heads of one bx adjacent).
// ---------------------------------------------------------------------------
__global__ __launch_bounds__(256) void k_gemmT_src(
    const bf16* __restrict__ WTm, const bf16* __restrict__ Xm, bf16* __restrict__ hgTm,
    const float* __restrict__ avm, float* __restrict__ srcm, float* __restrict__ dstm,
    unsigned* __restrict__ mxm,
    const bf16* __restrict__ WTd, const bf16* __restrict__ Xd, bf16* __restrict__ hgTd,
    const float* __restrict__ avd, float* __restrict__ srcd, float* __restrict__ dstd,
    unsigned* __restrict__ mxd)
{
    __shared__ float sred[4][2][64];
    const int wg = (blockIdx.x & 7) * 192 + (blockIdx.x >> 3);
    const int h = wg & 3;
    int bx = wg >> 2;
    const bf16 *WT, *X; bf16* hgT; const float* av;
    float *src, *dst; unsigned* mx; int nN, nLog;
    if (bx < 256) { WT = WTm; X = Xm; hgT = hgTm; av = avm; src = srcm; dst = dstm; mx = mxm; nN = 1024; nLog = 10; }
    else { bx -= 256; WT = WTd; X = Xd; hgT = hgTd; av = avd; src = srcd; dst = dstd; mx = mxd; nN = 512; nLog = 9; }
    const int d0 = h * 64, n0 = bx * 64;
    f32x4 acc[4] = {};
    gemm_bt_mn(WT, 256, X, 256, 256, d0, n0, acc);
    const int t = threadIdx.x, lane = t & 63, wv = t >> 6, lr = lane & 15, kq = lane >> 4;
    float a0c[4], a1c[4];
    *(float4*)a0c = *(const float4*)(av + h * 64 + wv * 16 + kq * 4);
    *(float4*)a1c = *(const float4*)(av + 256 + h * 64 + wv * 16 + kq * 4);
    #pragma unroll
    for (int nt = 0; nt < 4; ++nt) {
        int node = n0 + nt * 16 + lr;
        int b = node >> nLog;
        int j = node & (nN - 1);
        float p0 = 0.f, p1 = 0.f;
        #pragma unroll
        for (int i = 0; i < 4; ++i) {
            int d = d0 + wv * 16 + kq * 4 + i;
            bf16 vb = f2bf(acc[nt][i]);
            hgT[((long)(b * 256 + d) << nLog) + j] = vb;
            float vr = bf2f(vb);
            p0 += vr * a0c[i];
            p1 += vr * a1c[i];
        }
        p0 += __shfl_xor(p0, 16, 64); p0 += __shfl_xor(p0, 32, 64);
        p1 += __shfl_xor(p1, 16, 64); p1 += __shfl_xor(p1, 32, 64);
        if (kq == 0) { sred[wv][0][nt * 16 + lr] = p0; sred[wv][1][nt * 16 + lr] = p1; }
    }
    __syncthreads();
    if (t < 64) {
        float s0 = sred[0][0][t] + sred[1][0][t] + sred[2][0][t] + sred[3][0][t];
        float s1 = sred[0][1][t] + sred[1][1][t] + sred[2][1][t] + sred[3][1][t];
        int node = n0 + t;
        src[(long)node * 4 + h] = s0;
        dst[(long)node * 4 + h] = s1;
        float m = s1;
        #pragma unroll
        for (int o = 32; o; o >>= 1) m = fmaxf(m, __shfl_xor(m, o, 64));
        if (t == 0) atomicMax(&mx[(n0 >> nLog) * 4 + h], encf(m));
    }
}

// combined main+det GAT aggregation, round 12:
// block = (b, head, 64-row slice); 1536 blocks, 6 blocks/CU. All 4 waves share
// ONE head panel (L1 reuse); each wave owns one 16-row group. exp2 softmax.
__global__ __launch_bounds__(256) void k_gatagg3(
    const bf16* __restrict__ hgTm, const unsigned long long* __restrict__ adjmM,
    const float4* __restrict__ srcM, const unsigned* __restrict__ mxM,
    const float4* __restrict__ dstM, const float* __restrict__ resM, bf16* __restrict__ outM,
    const bf16* __restrict__ hgTd, const unsigned long long* __restrict__ adjmD,
    const float4* __restrict__ srcD, const unsigned* __restrict__ mxD,
    const float4* __restrict__ dstD, const float* __restrict__ resD, bf16* __restrict__ outD)
{
    const float L2E = 1.44269504f;
    __shared__ float dstT[1024];
    __shared__ unsigned adjW[64][33];
    int bid = (blockIdx.x & 7) * 192 + (blockIdx.x >> 3);
    const bf16* hgT; const unsigned long long* adjm; const float4* srcv;
    const unsigned* mxp; const float4* dstv; const float* res; bf16* outb;
    int nN, b, h, i0;
    if (bid < 1024) {
        hgT = hgTm; adjm = adjmM; srcv = srcM; mxp = mxM; dstv = dstM; res = resM; outb = outM;
        nN = 1024; b = bid >> 6; int r = bid & 63; h = r >> 4; i0 = (r & 15) << 6;
    } else {
        int b2 = bid - 1024;
        hgT = hgTd; adjm = adjmD; srcv = srcD; mxp = mxD; dstv = dstD; res = resD; outb = outD;
        nN = 512; b = b2 >> 5; int r = b2 & 31; h = r >> 3; i0 = (r & 7) << 6;
    }
    const int t = threadIdx.x;
    const int nW = nN >> 5;                 // 32-bit words per adj row
    const int sh = (nN == 1024) ? 5 : 4;
    for (int j = t; j < nN; j += 256)
        dstT[j] = ((const float*)(dstv + (long)b * nN + j))[h] * L2E;
    {
        const unsigned* adj32 = (const unsigned*)(adjm + (long)(b * nN + i0) * (nN >> 6));
        for (int idx = t; idx < (nW << 6); idx += 256) {
            int r = idx >> sh, c = idx & (nW - 1);
            adjW[r][c] = adj32[(long)r * nW + c];
        }
    }
    __syncthreads();
    const int lane = t & 63, wv = t >> 6, lr = lane & 15, kq = lane >> 4;
    const int ri = i0 + wv * 16;
    const float mdh = decf(mxp[b * 4 + h]) * L2E;
    float u, w, psum = 0.f;
    {
        int row = ri + lr;
        float s = ((const float*)(srcv + (long)b * nN + row))[h] * L2E;
        float tmp = s + mdh;
        float m = fmaxf(tmp, 0.2f * tmp);
        u = s - m;
        w = fmaf(0.2f, s, -m);
    }
    f32x4 acc[4] = {};
    const bf16* hb = hgT + ((long)b * 256 + h * 64) * nN;
    for (int j0 = 0; j0 < nN; j0 += 32) {
        bf16x8 bfr[4];
        #pragma unroll
        for (int nt = 0; nt < 4; ++nt)
            bfr[nt] = *(const bf16x8*)(hb + (long)(nt * 16 + lr) * nN + j0 + kq * 8);
        float4 d0 = *(const float4*)&dstT[j0 + kq * 8];
        float4 d1 = *(const float4*)&dstT[j0 + kq * 8 + 4];
        float dv[8] = {d0.x, d0.y, d0.z, d0.w, d1.x, d1.y, d1.z, d1.w};
        unsigned byte = (adjW[wv * 16 + lr][j0 >> 5] >> (kq * 8)) & 0xffu;
        bf16x8 af;
        #pragma unroll
        for (int jj = 0; jj < 8; ++jj) {
            float x = fmaxf(u + dv[jj], fmaf(0.2f, dv[jj], w));
            float p = exp2f(x);
            p = (byte & (1u << jj)) ? p : 0.f;
            af[jj] = f2bf(p);
            psum += p;
        }
        #pragma unroll
        for (int nt = 0; nt < 4; ++nt)
            acc[nt] = __builtin_amdgcn_mfma_f32_16x16x32_bf16(af, bfr[nt], acc[nt], 0, 0, 0);
    }
    float v = psum;
    v += __shfl_xor(v, 16, 64);
    v += __shfl_xor(v, 32, 64);
    float stot = v;
    #pragma unroll
    for (int ii = 0; ii < 4; ++ii) {
        int i = ri + kq * 4 + ii;
        long bi = (long)b * nN + i;
        float sv = __shfl(stot, kq * 4 + ii, 64);
        float rs = 1.f / fmaxf(sv, 1e-30f);
        #pragma unroll
        for (int nt = 0; nt < 4; ++nt) {
            int col = h * 64 + nt * 16 + lr;
            float a = acc[nt][ii] * rs;
            float e = a > 0.f ? a : expm1f(a);
            float vv = 0.5f * e + 0.5f * res[(long)b * 262144 + (long)i * 256 + col];
            outb[bi * 256 + col] = f2bf(vv);
        }
    }
}

// ---------------------------------------------------------------------------
extern "C" void kernel_launch(void* const* d_in, const int* in_sizes, int n_in,
                              void* d_out, int out_size, void* d_ws, size_t ws_size,
                              hipStream_t stream)
{
    (void)in_sizes; (void)n_in; (void)out_size; (void)ws_size;
    const float* tracks = (const float*)d_in[0];
    const float* dets   = (const float*)d_in[1];
    const int*  tmarks = (const int*)d_in[2];
    const int*  dmarks = (const int*)d_in[3];
    const float* W1   = (const float*)d_in[4];
    const float* b1   = (const float*)d_in[5];
    const float* W2   = (const float*)d_in[6];
    const float* b2   = (const float*)d_in[7];
    const float* Wqkv = (const float*)d_in[8];
    const float* Wo   = (const float*)d_in[9];
    const float* eff1 = (const float*)d_in[10];
    const float* eff2 = (const float*)d_in[11];
    const float* gatW = (const float*)d_in[12];
    const float* gatA = (const float*)d_in[13];
    const float* dgatW = (const float*)d_in[14];
    const float* dgatA = (const float*)d_in[15];
    const float* clsWq = (const float*)d_in[16];
    const float* clsWk = (const float*)d_in[17];
    float* out = (float*)d_out;

    char* wsb = (char*)d_ws;
    size_t off = 0;
    auto take = [&](size_t bytes) -> char* {
        char* p = wsb + off;
        off += (bytes + 255) & ~(size_t)255;
        return p;
    };
    char* R_emb  = take(37748736);   // x20(+0), h2_b(+8388608); det GAT bufs(+16M..)
    char* R_r0   = take(8388608);    // emb_r0_f
    char* R_hln  = take(33554432);   // hln; later f1_b
    char* R_v    = take(33554432);   // y main(+0) / det(+8388608)
    char* R_gat  = take(25165824);   // hgT_m(+0), xga_m(+8388608), xgb_m(+16777216)
    char* R_q    = take(4194304);    // q_b
    char* R_o0   = take(4194304);    // o0_b
    char* R_f0f  = take(16777216);   // feat0_f
    char* R_f0b  = take(8388608);    // feat0_b
    char* R_demb = take(4194304);    // demb_b
    float4* nodes = (float4*)take(262144);
    float4* src4  = (float4*)take(262144);
    float4* dst4  = (float4*)take(262144);
    unsigned* maxd_all = (unsigned*)take(1024);   // 4 layers x 16 b x 4 h
    unsigned long long* adjm_main = (unsigned long long*)take(2097152);
    unsigned long long* adjm_det  = (unsigned long long*)take(524288);
    bf16* wbuf = (bf16*)take(3014656);   // transposed bf16 weights + Wc
    float4* srcd4 = (float4*)take(131072);
    float4* dstd4 = (float4*)take(131072);

    float* emb_r0_f = (float*)R_r0;
    bf16*  hln      = (bf16*)R_hln;
    bf16*  kv_b     = (bf16*)d_out;         // 67MB scratch in d_out; dead before logits
    bf16*  q_b      = (bf16*)R_q;
    bf16*  o0_b     = (bf16*)R_o0;
    float* x20      = (float*)R_emb;
    bf16*  h2_b     = (bf16*)(R_emb + 8388608);
    bf16*  f1_b     = (bf16*)R_hln;
    float* feat0_f  = (float*)R_f0f;
    bf16*  feat0_b  = (bf16*)R_f0b;
    bf16*  demb_b   = (bf16*)R_demb;
    bf16*  hgT_m    = (bf16*)R_gat;
    bf16*  xga_m    = (bf16*)(R_gat + 8388608);
    bf16*  xgb_m    = (bf16*)(R_gat + 16777216);
    bf16*  hgT_d    = (bf16*)(R_emb + 16777216);   // x20/h2 dead once GAT starts
    bf16*  xga_d    = (bf16*)(R_emb + 20971520);
    bf16*  xgb_d    = (bf16*)(R_emb + 25165824);
    bf16*  y_m      = (bf16*)R_v;
    bf16*  y_d      = (bf16*)(R_v + 8388608);

    // transposed-weight table (+ plain cls copies for Wc)
    bf16* W2T    = wbuf + 0;
    bf16* WqkvT  = wbuf + 65536;
    bf16* WoT    = wbuf + 262144;
    bf16* eff1T  = wbuf + 327680;
    bf16* eff2T  = wbuf + 589824;
    bf16* gatW0T = wbuf + 851968;
    bf16* gatW1T = wbuf + 917504;
    bf16* dgatW0T= wbuf + 983040;
    bf16* dgatW1T= wbuf + 1048576;
    // plain copies: Wq0 @1114112, Wk0 @1179648, Wq1 @1245184, Wk1 @1310720
    bf16* WcT0   = wbuf + 1376256;
    bf16* WcT1   = wbuf + 1441792;
    PrepTab tab;
    tab.e[0]  = { W2,             0,       256,  256,  0,    1 };
    tab.e[1]  = { Wqkv,           65536,   256,  768,  64,   1 };
    tab.e[2]  = { Wo,             262144,  256,  256,  256,  1 };
    tab.e[3]  = { eff1,           327680,  256,  1024, 320,  1 };
    tab.e[4]  = { eff2,           589824,  1024, 256,  576,  1 };
    tab.e[5]  = { gatW,           851968,  256,  256,  832,  1 };
    tab.e[6]  = { gatW + 65536,   917504,  256,  256,  896,  1 };
    tab.e[7]  = { dgatW,          983040,  256,  256,  960,  1 };
    tab.e[8]  = { dgatW + 65536,  1048576, 256,  256,  1024, 1 };
    tab.e[9]  = { clsWq,          1114112, 256,  256,  1088, 0 };
    tab.e[10] = { clsWk,          1179648, 256,  256,  1152, 0 };
    tab.e[11] = { clsWq + 65536,  1245184, 256,  256,  1216, 0 };
    tab.e[12] = { clsWk + 65536,  1310720, 256,  256,  1280, 0 };

    // prep + graph + embeddings (+fused LN for track rows)
    k_prep<<<1344, 256, 0, stream>>>(tab, wbuf);
    k_wcomb<<<32, 256, 0, stream>>>(wbuf);
    k_nodes<<<64, 256, 0, stream>>>(tracks, dets, tmarks, dmarks, nodes, maxd_all);
    k_adjmask<<<768, 256, 0, stream>>>(nodes, adjm_main, adjm_det);
    k_featgemm<<<1152, 256, 0, stream>>>(tracks, dets, W1, b1, W2T, b2,
        hln, emb_r0_f, feat0_f, feat0_b, demb_b);

    // encoder (only r=0 row needed downstream of attention)
    k_kvq<<<2176, 256, 0, stream>>>(hln, WqkvT, kv_b, q_b);
    k_attn<<<8192, 256, 0, stream>>>(q_b, kv_b, o0_b);
    k_addres_ln<<<128, 256, 0, stream>>>(o0_b, WoT, emb_r0_f, x20, h2_b);
    k_gemm128_bf16<<<dim3(8, 64, 1), 256, 0, stream>>>(h2_b, 256, eff1T, 256, f1_b, 1024, 256, 1);
    k_gemm_pred<<<dim3(4, 128, 1), 256, 0, stream>>>(f1_b, 1024, eff2T, 1024, emb_r0_f, x20, feat0_f, feat0_b, 1024);

    // GAT layer 1 (main + det combined)
    k_gemmT_src<<<1536, 256, 0, stream>>>(
        gatW0T, feat0_b, hgT_m, gatA, (float*)src4, (float*)dst4, maxd_all,
        dgatW0T, demb_b, hgT_d, dgatA, (float*)srcd4, (float*)dstd4, maxd_all + 128);
    k_gatagg3<<<1536, 256, 0, stream>>>(
        hgT_m, adjm_main, src4, maxd_all, dst4, feat0_f, xga_m,
        hgT_d, adjm_det, srcd4, maxd_all + 128, dstd4, feat0_f + 131072, xga_d);
    // GAT layer 2 (main + det combined)
    k_gemmT_src<<<1536, 256, 0, stream>>>(
        gatW1T, xga_m, hgT_m, gatA + 512, (float*)src4, (float*)dst4, maxd_all + 64,
        dgatW1T, xga_d, hgT_d, dgatA + 512, (float*)srcd4, (float*)dstd4, maxd_all + 192);
    k_gatagg3<<<1536, 256, 0, stream>>>(
        hgT_m, adjm_main, src4, maxd_all + 64, dst4, feat0_f, xgb_m,
        hgT_d, adjm_det, srcd4, maxd_all + 192, dstd4, feat0_f + 131072, xgb_d);

    // y = x @ Wc, then logits = y @ x^T (main + det combined)
    k_y<<<1536, 256, 0, stream>>>(xgb_m, WcT0, y_m, xgb_d, WcT1, y_d);
    k_logits<<<1280, 256, 0, stream>>>(y_m, xgb_m, y_d, xgb_d, adjm_main, adjm_det,
        out, out + 20971520L);
}

// Round 7
// 500.945 us; speedup vs baseline: 1.1332x; 1.1332x over previous
//
#include <hip/hip_runtime.h>
#include <math.h>

// ScatterNet — round 13:
// - k_gatagg4: round-5 shape (768 blocks, 128 rows/block, mt=2) + LDS-staged
//   panel strips. Global panel reads become coalesced-along-j (16 seg/inst vs
//   64), MFMA fragments come from LDS pan[2][64][40] (proven GEMM pattern).
// - everything else as round 11/12 (best 494us config).

typedef __bf16 bf16;
typedef __bf16 bf16x8 __attribute__((ext_vector_type(8)));
typedef __bf16 bf16x4 __attribute__((ext_vector_type(4)));
typedef float f32x4 __attribute__((ext_vector_type(4)));

__device__ __forceinline__ float bf2f(bf16 x) { return (float)x; }
__device__ __forceinline__ bf16 f2bf(float x) { return (bf16)x; }

// monotone float<->uint for atomicMax on signed floats
__device__ __forceinline__ unsigned encf(float f) {
    unsigned u = __float_as_uint(f);
    return (u & 0x80000000u) ? ~u : (u | 0x80000000u);
}
__device__ __forceinline__ float decf(unsigned u) {
    return (u & 0x80000000u) ? __uint_as_float(u & 0x7fffffffu)
                             : __uint_as_float(~u);
}

// ---------------------------------------------------------------------------
// Weight prep: fp32 [R][C] -> bf16; trans=1: [C][R], trans=0: [R][C] copy.
// ---------------------------------------------------------------------------
struct PrepEnt { const float* src; long dofs; int R; int C; int tstart; int trans; };
struct PrepTab { PrepEnt e[13]; };

__global__ __launch_bounds__(256) void k_prep(PrepTab tab, bf16* __restrict__ dst)
{
    __shared__ float tile[32][33];
    const int tid = blockIdx.x;
    int k = 0;
    #pragma unroll
    for (int q = 1; q < 13; ++q) if (tid >= tab.e[q].tstart) k = q;
    PrepEnt E = tab.e[k];
    const int local = tid - E.tstart;
    const int cT = E.C >> 5;
    const int tr = local / cT, tc = local - tr * cT;
    const int r0 = tr << 5, c0 = tc << 5;
    const int t = threadIdx.x;
    {
        int r = t >> 3, cq = (t & 7) * 4;
        *(float4*)&tile[r][cq] = *(const float4*)(E.src + (long)(r0 + r) * E.C + c0 + cq);
    }
    __syncthreads();
    if (E.trans) {
        int c = t >> 3, rq = (t & 7) * 4;
        bf16x4 o;
        o[0] = f2bf(tile[rq + 0][c]); o[1] = f2bf(tile[rq + 1][c]);
        o[2] = f2bf(tile[rq + 2][c]); o[3] = f2bf(tile[rq + 3][c]);
        *(bf16x4*)(dst + E.dofs + (long)(c0 + c) * E.R + r0 + rq) = o;
    } else {
        int r = t >> 3, cq = (t & 7) * 4;
        bf16x4 o;
        o[0] = f2bf(tile[r][cq + 0]); o[1] = f2bf(tile[r][cq + 1]);
        o[2] = f2bf(tile[r][cq + 2]); o[3] = f2bf(tile[r][cq + 3]);
        *(bf16x4*)(dst + E.dofs + (long)(r0 + r) * E.C + c0 + cq) = o;
    }
}

// ---------------------------------------------------------------------------
// 64x64 MFMA GEMM core. D: row = m0 + wv*16 + kq*4 + i, col = n0 + nt*16 + lr.
// ---------------------------------------------------------------------------
__device__ __forceinline__ void gemm_bt_mn(const bf16* __restrict__ A, int lda,
                                           const bf16* __restrict__ BT, int ldb,
                                           int K, int m0, int n0, f32x4 acc[4])
{
    __shared__ bf16 As[64][40];
    __shared__ bf16 Bs[64][40];
    const int t = threadIdx.x;
    const int lane = t & 63, wv = t >> 6, lr = lane & 15, kq = lane >> 4;
    const int arow = t >> 2, acol = (t & 3) * 8;
    for (int k0 = 0; k0 < K; k0 += 32) {
        __syncthreads();
        *(uint4*)&As[arow][acol] = *(const uint4*)(A + (long)(m0 + arow) * lda + k0 + acol);
        *(uint4*)&Bs[arow][acol] = *(const uint4*)(BT + (long)(n0 + arow) * ldb + k0 + acol);
        __syncthreads();
        bf16x8 af = *(const bf16x8*)&As[wv * 16 + lr][kq * 8];
        #pragma unroll
        for (int nt = 0; nt < 4; ++nt) {
            bf16x8 bfr = *(const bf16x8*)&Bs[nt * 16 + lr][kq * 8];
            acc[nt] = __builtin_amdgcn_mfma_f32_16x16x32_bf16(af, bfr, acc[nt], 0, 0, 0);
        }
    }
}

__device__ __forceinline__ void gemm_bt(const bf16* __restrict__ A, int lda,
                                        const bf16* __restrict__ BT, int ldb,
                                        int K, f32x4 acc[4])
{
    gemm_bt_mn(A, lda, BT, ldb, K, blockIdx.y * 64, blockIdx.x * 64, acc);
}

// ---------------------------------------------------------------------------
// 128x128 MFMA GEMM core (BK=32), used by kvq / eff1.
// ---------------------------------------------------------------------------
__device__ __forceinline__ void gemm128_core(const bf16* __restrict__ A, int lda,
                                             const bf16* __restrict__ BT, int ldb,
                                             int m0, int n0, int K, f32x4 acc[2][8])
{
    __shared__ bf16 As[128][40];
    __shared__ bf16 Bs[128][40];
    const int t = threadIdx.x;
    const int lane = t & 63, wv = t >> 6, lr = lane & 15, kq = lane >> 4;
    const int srow = t >> 1, scol = (t & 1) * 16;
    for (int k0 = 0; k0 < K; k0 += 32) {
        __syncthreads();
        {
            const bf16* ap = A + (long)(m0 + srow) * lda + k0 + scol;
            *(uint4*)&As[srow][scol] = *(const uint4*)ap;
            *(uint4*)&As[srow][scol + 8] = *(const uint4*)(ap + 8);
            const bf16* bp = BT + (long)(n0 + srow) * ldb + k0 + scol;
            *(uint4*)&Bs[srow][scol] = *(const uint4*)bp;
            *(uint4*)&Bs[srow][scol + 8] = *(const uint4*)(bp + 8);
        }
        __syncthreads();
        bf16x8 af[2];
        af[0] = *(const bf16x8*)&As[wv * 32 + lr][kq * 8];
        af[1] = *(const bf16x8*)&As[wv * 32 + 16 + lr][kq * 8];
        #pragma unroll
        for (int nt = 0; nt < 8; ++nt) {
            bf16x8 bfr = *(const bf16x8*)&Bs[nt * 16 + lr][kq * 8];
            acc[0][nt] = __builtin_amdgcn_mfma_f32_16x16x32_bf16(af[0], bfr, acc[0][nt], 0, 0, 0);
            acc[1][nt] = __builtin_amdgcn_mfma_f32_16x16x32_bf16(af[1], bfr, acc[1][nt], 0, 0, 0);
        }
    }
}

// eff1 GEMM (relu)
__global__ __launch_bounds__(256) void k_gemm128_bf16(
    const bf16* __restrict__ A, int lda,
    const bf16* __restrict__ BT, int ldb,
    bf16* __restrict__ out, int ldo, int K, int relu)
{
    f32x4 acc[2][8] = {};
    const int m0 = blockIdx.y * 128, n0 = blockIdx.x * 128;
    gemm128_core(A, lda, BT, ldb, m0, n0, K, acc);
    const int lane = threadIdx.x & 63, wv = threadIdx.x >> 6;
    const int lr = lane & 15, kq = lane >> 4;
    #pragma unroll
    for (int mt = 0; mt < 2; ++mt) {
        #pragma unroll
        for (int nt = 0; nt < 8; ++nt) {
            int col = n0 + nt * 16 + lr;
            #pragma unroll
            for (int i = 0; i < 4; ++i) {
                int row = m0 + wv * 32 + mt * 16 + kq * 4 + i;
                float v = acc[mt][nt][i];
                if (relu) v = fmaxf(v, 0.f);
                out[(long)row * ldo + col] = f2bf(v);
            }
        }
    }
}

// combined KV + q projection (one launch), XCD-chunked swizzle
__global__ __launch_bounds__(256) void k_kvq(
    const bf16* __restrict__ hln, const bf16* __restrict__ WqkvT,
    bf16* __restrict__ kv, bf16* __restrict__ q)
{
    const int wg = (blockIdx.x & 7) * 272 + (blockIdx.x >> 3);
    const bf16* A; const bf16* BT; bf16* out;
    int lda, ldo, m0, n0;
    if (wg < 2048) {           // KV: 65536 rows x 512 cols
        A = hln; lda = 256; BT = WqkvT + 65536;
        m0 = (wg >> 2) * 128; n0 = (wg & 3) * 128;
        out = kv; ldo = 512;
    } else {                    // q: 8192 rows (stride-8 rows of hln) x 256 cols
        int t2 = wg - 2048;
        A = hln; lda = 2048; BT = WqkvT;
        m0 = (t2 >> 1) * 128; n0 = (t2 & 1) * 128;
        out = q; ldo = 256;
    }
    f32x4 acc[2][8] = {};
    gemm128_core(A, lda, BT, 256, m0, n0, 256, acc);
    const int lane = threadIdx.x & 63, wv = threadIdx.x >> 6;
    const int lr = lane & 15, kq = lane >> 4;
    #pragma unroll
    for (int mt = 0; mt < 2; ++mt) {
        #pragma unroll
        for (int nt = 0; nt < 8; ++nt) {
            int col = n0 + nt * 16 + lr;
            #pragma unroll
            for (int i = 0; i < 4; ++i) {
                int row = m0 + wv * 32 + mt * 16 + kq * 4 + i;
                out[(long)row * ldo + col] = f2bf(acc[mt][nt][i]);
            }
        }
    }
}

// Wc^T = Wk @ Wq^T (bf16), per cls head. 32 blocks.
__global__ __launch_bounds__(256) void k_wcomb(bf16* __restrict__ wb)
{
    const int bid = blockIdx.x;
    const int head = bid >> 4, r = bid & 15;
    const bf16* A  = wb + 1179648 + head * 131072;   // Wk plain
    const bf16* BT = wb + 1114112 + head * 131072;   // Wq plain
    bf16* out = wb + 1376256 + head * 65536;         // WcT
    const int m0 = (r >> 2) * 64, n0 = (r & 3) * 64;
    f32x4 acc[4] = {};
    gemm_bt_mn(A, 256, BT, 256, 256, m0, n0, acc);
    const int lane = threadIdx.x & 63, wv = threadIdx.x >> 6;
    const int lr = lane & 15, kq = lane >> 4;
    #pragma unroll
    for (int nt = 0; nt < 4; ++nt) {
        int col = n0 + nt * 16 + lr;
        #pragma unroll
        for (int i = 0; i < 4; ++i) {
            int row = m0 + wv * 16 + kq * 4 + i;
            out[(long)row * 256 + col] = f2bf(acc[nt][i]);
        }
    }
}

// y = x @ Wc (main + det combined), XCD-chunked swizzle
__global__ __launch_bounds__(256) void k_y(
    const bf16* __restrict__ xm, const bf16* __restrict__ WcT0, bf16* __restrict__ ym,
    const bf16* __restrict__ xd, const bf16* __restrict__ WcT1, bf16* __restrict__ yd)
{
    const int wg = (blockIdx.x & 7) * 192 + (blockIdx.x >> 3);
    int by = wg >> 2;
    const int bx = wg & 3;
    const bf16 *A, *BT; bf16* out;
    if (by < 256) { A = xm; BT = WcT0; out = ym; }
    else          { by -= 256; A = xd; BT = WcT1; out = yd; }
    f32x4 acc[4] = {};
    const int m0 = by * 64, n0 = bx * 64;
    gemm_bt_mn(A, 256, BT, 256, 256, m0, n0, acc);
    const int lane = threadIdx.x & 63, wv = threadIdx.x >> 6;
    const int lr = lane & 15, kq = lane >> 4;
    #pragma unroll
    for (int nt = 0; nt < 4; ++nt) {
        int col = n0 + nt * 16 + lr;
        #pragma unroll
        for (int i = 0; i < 4; ++i) {
            int row = m0 + wv * 16 + kq * 4 + i;
            out[(long)row * 256 + col] = f2bf(acc[nt][i]);
        }
    }
}

// logits = y @ x^T, sigmoid(/16)*adj epilogue. BK=64 core, XCD swizzle.
__global__ __launch_bounds__(256) void k_logits(
    const bf16* __restrict__ ym, const bf16* __restrict__ xm,
    const bf16* __restrict__ yd, const bf16* __restrict__ xd,
    const unsigned long long* __restrict__ adjmM,
    const unsigned long long* __restrict__ adjmD,
    float* __restrict__ out, float* __restrict__ asso)
{
    const int wg = (blockIdx.x & 7) * 160 + (blockIdx.x >> 3);
    const bf16 *A, *BT; float* ob; const unsigned long long* adjm;
    int ldo, nN, nC, flags, m0, n0, z;
    if (wg < 1024) {
        z = wg >> 6; int r = wg & 63;
        m0 = (r >> 3) * 128; n0 = (r & 7) * 128;
        A = ym + (long)z * 262144; BT = xm + (long)z * 262144;
        ob = out + (long)z * 1048576; ldo = 1024;
        adjm = adjmM; nN = 1024; nC = 16; flags = 1;
    } else {
        int t2 = wg - 1024;
        z = t2 >> 4; int r = t2 & 15;
        m0 = (r >> 2) * 128; n0 = (r & 3) * 128;
        A = yd + (long)z * 131072; BT = xd + (long)z * 131072;
        ob = out + 16777216 + (long)z * 262144; ldo = 512;
        adjm = adjmD; nN = 512; nC = 8; flags = 2;
    }
    const int t = threadIdx.x;
    const int lane = t & 63, wv = t >> 6, lr = lane & 15, kq = lane >> 4;
    f32x4 acc[2][8] = {};
    {
        __shared__ bf16 As[128][72];
        __shared__ bf16 Bs[128][72];
        const int srow4 = t >> 3, scol8 = (t & 7) * 8;
        for (int k0 = 0; k0 < 256; k0 += 64) {
            __syncthreads();
            #pragma unroll
            for (int p = 0; p < 4; ++p) {
                int row = p * 32 + srow4;
                *(uint4*)&As[row][scol8] = *(const uint4*)(A + (long)(m0 + row) * 256 + k0 + scol8);
                *(uint4*)&Bs[row][scol8] = *(const uint4*)(BT + (long)(n0 + row) * 256 + k0 + scol8);
            }
            __syncthreads();
            #pragma unroll
            for (int ks = 0; ks < 64; ks += 32) {
                bf16x8 af[2];
                af[0] = *(const bf16x8*)&As[wv * 32 + lr][kq * 8 + ks];
                af[1] = *(const bf16x8*)&As[wv * 32 + 16 + lr][kq * 8 + ks];
                #pragma unroll
                for (int nt = 0; nt < 8; ++nt) {
                    bf16x8 bfr = *(const bf16x8*)&Bs[nt * 16 + lr][kq * 8 + ks];
                    acc[0][nt] = __builtin_amdgcn_mfma_f32_16x16x32_bf16(af[0], bfr, acc[0][nt], 0, 0, 0);
                    acc[1][nt] = __builtin_amdgcn_mfma_f32_16x16x32_bf16(af[1], bfr, acc[1][nt], 0, 0, 0);
                }
            }
        }
    }
    #pragma unroll
    for (int mt = 0; mt < 2; ++mt) {
        #pragma unroll
        for (int i = 0; i < 4; ++i) {
            int row = m0 + wv * 32 + mt * 16 + kq * 4 + i;
            unsigned long long w0 = adjm[((long)z * nN + row) * nC + (n0 >> 6)];
            unsigned long long w1 = adjm[((long)z * nN + row) * nC + (n0 >> 6) + 1];
            #pragma unroll
            for (int nt = 0; nt < 8; ++nt) {
                int col = n0 + nt * 16 + lr;
                int bp = nt * 16 + lr;
                bool adj = (bp < 64) ? ((w0 >> bp) & 1ull) : ((w1 >> (bp - 64)) & 1ull);
                if ((flags & 2) && row == col) adj = false;
                float v = 0.f;
                if (adj) v = 1.f / (1.f + __expf(-acc[mt][nt][i] * 0.0625f));
                ob[(long)row * ldo + col] = v;
                if ((flags & 1) && row < 512 && col >= 512)
                    asso[(long)z * 262144 + (long)row * 512 + (col - 512)] = v;
            }
        }
    }
}

// predicted = tr_emb0 + 0.9*(x2_0 + ff2_out); scattered to feat0[b*1024+m]
__global__ __launch_bounds__(256) void k_gemm_pred(
    const bf16* __restrict__ A, int lda,
    const bf16* __restrict__ BT, int ldb,
    const float* __restrict__ res1, const float* __restrict__ res2,
    float* __restrict__ outf, bf16* __restrict__ outb, int K)
{
    f32x4 acc[4] = {};
    gemm_bt(A, lda, BT, ldb, K, acc);
    const int lane = threadIdx.x & 63, wv = threadIdx.x >> 6;
    const int lr = lane & 15, kq = lane >> 4;
    const int m0 = blockIdx.y * 64, n0 = blockIdx.x * 64;
    #pragma unroll
    for (int nt = 0; nt < 4; ++nt) {
        int col = n0 + nt * 16 + lr;
        #pragma unroll
        for (int i = 0; i < 4; ++i) {
            int row = m0 + wv * 16 + kq * 4 + i;     // b*512 + m
            float v = res1[(long)row * 256 + col]
                    + 0.9f * (res2[(long)row * 256 + col] + acc[nt][i]);
            long drow = (long)row + ((row >> 9) << 9);   // b*1024 + m
            long o = drow * 256 + col;
            outf[o] = v;
            outb[o] = f2bf(v);
        }
    }
}

// ---------------------------------------------------------------------------
// fused feat MLP + LayerNorm epilogue (track rows). 64 rows x 256 cols/block.
// ---------------------------------------------------------------------------
__global__ __launch_bounds__(256) void k_featgemm(
    const float* __restrict__ tracks, const float* __restrict__ dets,
    const float* __restrict__ W1, const float* __restrict__ b1,
    const bf16* __restrict__ W2T, const float* __restrict__ b2,
    bf16* __restrict__ hln, float* __restrict__ emb_r0_f,
    float* __restrict__ feat0_f, bf16* __restrict__ feat0_b,
    bf16* __restrict__ demb_b)
{
    __shared__ float xr[64][4];
    __shared__ float w1s[4][256];
    __shared__ float b1s[256];
    __shared__ bf16 As[64][40];
    __shared__ bf16 Bs[256][40];
    const int t = threadIdx.x;
    const int m0 = blockIdx.x * 64;
    if (t < 64) {
        int gr = m0 + t;
        const float* sp = (gr < 65536) ? (tracks + (long)gr * 4)
                                       : (dets + (long)(gr - 65536) * 4);
        *(float4*)&xr[t][0] = *(const float4*)sp;
    }
    w1s[0][t] = W1[t];       w1s[1][t] = W1[256 + t];
    w1s[2][t] = W1[512 + t]; w1s[3][t] = W1[768 + t];
    b1s[t] = b1[t];
    const int arow = t >> 2, acol = (t & 3) * 8;
    const int lane = t & 63, wv = t >> 6, lr = lane & 15, kq = lane >> 4;
    f32x4 acc[16] = {};
    __syncthreads();
    for (int k0 = 0; k0 < 256; k0 += 32) {
        __syncthreads();
        #pragma unroll
        for (int j = 0; j < 8; ++j) {
            int c = k0 + acol + j;
            float v = fmaf(xr[arow][0], w1s[0][c],
                      fmaf(xr[arow][1], w1s[1][c],
                      fmaf(xr[arow][2], w1s[2][c],
                      fmaf(xr[arow][3], w1s[3][c], b1s[c]))));
            v = v > 0.f ? v : (__expf(v) - 1.f);
            As[arow][acol + j] = f2bf(v);
        }
        #pragma unroll
        for (int rr = 0; rr < 4; ++rr) {
            int n = rr * 64 + (t >> 2);
            *(uint4*)&Bs[n][acol] = *(const uint4*)(W2T + (long)n * 256 + k0 + acol);
        }
        __syncthreads();
        bf16x8 af = *(const bf16x8*)&As[wv * 16 + lr][kq * 8];
        #pragma unroll
        for (int nt = 0; nt < 16; ++nt) {
            bf16x8 bfr = *(const bf16x8*)&Bs[nt * 16 + lr][kq * 8];
            acc[nt] = __builtin_amdgcn_mfma_f32_16x16x32_bf16(af, bfr, acc[nt], 0, 0, 0);
        }
    }
    if (m0 < 65536) {
        #pragma unroll
        for (int nt = 0; nt < 16; ++nt) {
            int col = nt * 16 + lr;
            float bv = b2[col];
            #pragma unroll
            for (int i = 0; i < 4; ++i) {
                int gr = m0 + wv * 16 + kq * 4 + i;
                float v = acc[nt][i] + bv;
                if ((gr & 7) == 0) emb_r0_f[(long)(gr >> 3) * 256 + col] = v;
                acc[nt][i] = bf2f(f2bf(v));   // bit-match old bf16 emb path
            }
        }
        float mean[4], rstd[4];
        #pragma unroll
        for (int i = 0; i < 4; ++i) {
            float s1 = 0.f, s2 = 0.f;
            #pragma unroll
            for (int nt = 0; nt < 16; ++nt) {
                float v = acc[nt][i];
                s1 += v; s2 += v * v;
            }
            #pragma unroll
            for (int o = 1; o < 16; o <<= 1) {
                s1 += __shfl_xor(s1, o, 64);
                s2 += __shfl_xor(s2, o, 64);
            }
            float mu = s1 * (1.f / 256.f);
            mean[i] = mu;
            rstd[i] = rsqrtf(fmaxf(s2 * (1.f / 256.f) - mu * mu, 0.f) + 1e-5f);
        }
        #pragma unroll
        for (int nt = 0; nt < 16; ++nt) {
            int col = nt * 16 + lr;
            #pragma unroll
            for (int i = 0; i < 4; ++i) {
                int gr = m0 + wv * 16 + kq * 4 + i;
                hln[(long)gr * 256 + col] = f2bf((acc[nt][i] - mean[i]) * rstd[i]);
            }
        }
    } else {
        #pragma unroll
        for (int nt = 0; nt < 16; ++nt) {
            int col = nt * 16 + lr;
            float bv = b2[col];
            #pragma unroll
            for (int i = 0; i < 4; ++i) {
                int gr = m0 + wv * 16 + kq * 4 + i;
                float v = acc[nt][i] + bv;
                int dr = gr - 65536;
                long drow = ((long)(dr >> 9) << 10) + 512 + (dr & 511);
                feat0_f[drow * 256 + col] = v;
                feat0_b[drow * 256 + col] = f2bf(v);
                demb_b[(long)dr * 256 + col] = f2bf(v);
            }
        }
    }
}

// adjacency bitmask: LDS-staged nodes, 32 rows per block.
__global__ __launch_bounds__(256) void k_adjmask(
    const float4* __restrict__ nodes,
    unsigned long long* __restrict__ adjm_main,
    unsigned long long* __restrict__ adjm_det)
{
    __shared__ float4 nds[1024];
    int bid = blockIdx.x;
    int nN, b, i0, nodeOfs;
    unsigned long long* adjm;
    if (bid < 512) { nN = 1024; b = bid >> 5; i0 = (bid & 31) << 5; nodeOfs = 0; adjm = adjm_main; }
    else { int b2 = bid - 512; nN = 512; b = b2 >> 4; i0 = (b2 & 15) << 5; nodeOfs = 512; adjm = adjm_det; }
    const float4* nb = nodes + b * 1024 + nodeOfs;
    const int t = threadIdx.x;
    for (int j = t; j < nN; j += 256) nds[j] = nb[j];
    __syncthreads();
    const int w = t >> 6, l = t & 63;
    const int nC = nN >> 6;
    for (int ii = 0; ii < 8; ++ii) {
        int i = i0 + w * 8 + ii;
        float4 ni = nds[i];
        for (int c = 0; c < nC; ++c) {
            float4 nj = nds[c * 64 + l];
            float dx = ni.x - nj.x, dy = ni.y - nj.y;
            bool adj = (dx * dx + dy * dy < 4.f) && (ni.z + nj.z < 1.f);
            unsigned long long mask = __ballot(adj);
            if (l == 0) adjm[(long)(b * nN + i) * nC + c] = mask;
        }
    }
}

// Wo-residual + LayerNorm, wide-N: 64 rows x 256 cols/block.
__global__ __launch_bounds__(256) void k_addres_ln(
    const bf16* __restrict__ A, const bf16* __restrict__ BT,
    const float* __restrict__ res1,
    float* __restrict__ x2out, bf16* __restrict__ h2)
{
    __shared__ bf16 As[64][40];
    __shared__ bf16 Bs[256][40];
    const int t = threadIdx.x;
    const int m0 = blockIdx.x * 64;
    const int arow = t >> 2, acol = (t & 3) * 8;
    const int lane = t & 63, wv = t >> 6, lr = lane & 15, kq = lane >> 4;
    f32x4 acc[16] = {};
    for (int k0 = 0; k0 < 256; k0 += 32) {
        __syncthreads();
        *(uint4*)&As[arow][acol] = *(const uint4*)(A + (long)(m0 + arow) * 256 + k0 + acol);
        #pragma unroll
        for (int rr = 0; rr < 4; ++rr) {
            int n = rr * 64 + (t >> 2);
            *(uint4*)&Bs[n][acol] = *(const uint4*)(BT + (long)n * 256 + k0 + acol);
        }
        __syncthreads();
        bf16x8 af = *(const bf16x8*)&As[wv * 16 + lr][kq * 8];
        #pragma unroll
        for (int nt = 0; nt < 16; ++nt) {
            bf16x8 bfr = *(const bf16x8*)&Bs[nt * 16 + lr][kq * 8];
            acc[nt] = __builtin_amdgcn_mfma_f32_16x16x32_bf16(af, bfr, acc[nt], 0, 0, 0);
        }
    }
    float mean[4], rstd[4];
    #pragma unroll
    for (int i = 0; i < 4; ++i) {
        int row = m0 + wv * 16 + kq * 4 + i;
        float s1 = 0.f, s2 = 0.f;
        #pragma unroll
        for (int nt = 0; nt < 16; ++nt) {
            float v = res1[(long)row * 256 + nt * 16 + lr] + acc[nt][i];
            acc[nt][i] = v;
            s1 += v; s2 += v * v;
        }
        #pragma unroll
        for (int o = 1; o < 16; o <<= 1) {
            s1 += __shfl_xor(s1, o, 64);
            s2 += __shfl_xor(s2, o, 64);
        }
        float mu = s1 * (1.f / 256.f);
        mean[i] = mu;
        rstd[i] = rsqrtf(fmaxf(s2 * (1.f / 256.f) - mu * mu, 0.f) + 1e-5f);
    }
    #pragma unroll
    for (int nt = 0; nt < 16; ++nt) {
        int col = nt * 16 + lr;
        #pragma unroll
        for (int i = 0; i < 4; ++i) {
            int row = m0 + wv * 16 + kq * 4 + i;
            float v = acc[nt][i];
            x2out[(long)row * 256 + col] = v;
            h2[(long)row * 256 + col] = f2bf((v - mean[i]) * rstd[i]);
        }
    }
}

// encoder attention, r=0 row only. kv layout: [row][512]
__global__ __launch_bounds__(256) void k_attn(
    const bf16* __restrict__ q, const bf16* __restrict__ kv,
    bf16* __restrict__ o0)
{
    const long t = blockIdx.x;
    const int h = threadIdx.x >> 6;
    const int lane = threadIdx.x & 63;
    const int s = lane >> 3;
    const int dg = lane & 7;
    const bf16* qp = q + t * 256 + h * 64 + dg * 8;
    const bf16* kp = kv + (t * 8 + s) * 512 + h * 64 + dg * 8;
    float p = 0.f;
    #pragma unroll
    for (int e = 0; e < 8; ++e) p += bf2f(qp[e]) * bf2f(kp[e]);
    p += __shfl_xor(p, 1, 64);
    p += __shfl_xor(p, 2, 64);
    p += __shfl_xor(p, 4, 64);
    float sc = p * 0.125f;
    float w[8];
    float mx = -1e30f;
    #pragma unroll
    for (int s2 = 0; s2 < 8; ++s2) { w[s2] = __shfl(sc, s2 * 8, 64); mx = fmaxf(mx, w[s2]); }
    float sum = 0.f;
    #pragma unroll
    for (int s2 = 0; s2 < 8; ++s2) { w[s2] = __expf(w[s2] - mx); sum += w[s2]; }
    float rs = 1.f / sum;
    float acc = 0.f;
    const bf16* vp = kv + (t * 8) * 512 + 256 + h * 64 + lane;
    #pragma unroll
    for (int s2 = 0; s2 < 8; ++s2) acc += w[s2] * bf2f(vp[(long)s2 * 512]);
    o0[t * 256 + h * 64 + lane] = f2bf(acc * rs);
}

__global__ __launch_bounds__(256) void k_nodes(
    const float* __restrict__ tracks, const float* __restrict__ dets,
    const int* __restrict__ tm, const int* __restrict__ dm,
    float4* __restrict__ nodes, unsigned* __restrict__ maxd_all)
{
    int idx = blockIdx.x * 256 + threadIdx.x;
    if (blockIdx.x == 0) maxd_all[threadIdx.x] = 0x007fffffu;   // enc(-inf), 4 layers x 64
    int b = idx >> 10;
    int i = idx & 1023;
    float x, y;
    int valid;
    if (i < 512) {
        long o = (long)(b * 512 + i) * 32;
        x = tracks[o]; y = tracks[o + 1];
        valid = (i < tm[b]) ? 1 : 0;
    } else {
        int n = i - 512;
        long o = (long)(b * 512 + n) * 4;
        x = dets[o]; y = dets[o + 1];
        valid = (n < dm[b]) ? 1 : 0;
    }
    nodes[idx] = make_float4(x, y, valid ? 0.f : 1e9f, 0.f);
}

// ---------------------------------------------------------------------------
// combined main+det GAT projection (transposed out) with FUSED src/dst dots.
// 1D grid, logical wg: head = wg&3, bx = wg>>2 (4 heads of one bx adjacent).
// ---------------------------------------------------------------------------
__global__ __launch_bounds__(256) void k_gemmT_src(
    const bf16* __restrict__ WTm, const bf16* __restrict__ Xm, bf16* __restrict__ hgTm,
    const float* __restrict__ avm, float* __restrict__ srcm, float* __restrict__ dstm,
    unsigned* __restrict__ mxm,
    const bf16* __restrict__ WTd, const bf16* __restrict__ Xd, bf16* __restrict__ hgTd,
    const float* __restrict__ avd, float* __restrict__ srcd, float* __restrict__ dstd,
    unsigned* __restrict__ mxd)
{
    __shared__ float sred[4][2][64];
    const int wg = (blockIdx.x & 7) * 192 + (blockIdx.x >> 3);
    const int h = wg & 3;
    int bx = wg >> 2;
    const bf16 *WT, *X; bf16* hgT; const float* av;
    float *src, *dst; unsigned* mx; int nN, nLog;
    if (bx < 256) { WT = WTm; X = Xm; hgT = hgTm; av = avm; src = srcm; dst = dstm; mx = mxm; nN = 1024; nLog = 10; }
    else { bx -= 256; WT = WTd; X = Xd; hgT = hgTd; av = avd; src = srcd; dst = dstd; mx = mxd; nN = 512; nLog = 9; }
    const int d0 = h * 64, n0 = bx * 64;
    f32x4 acc[4] = {};
    gemm_bt_mn(WT, 256, X, 256, 256, d0, n0, acc);
    const int t = threadIdx.x, lane = t & 63, wv = t >> 6, lr = lane & 15, kq = lane >> 4;
    float a0c[4], a1c[4];
    *(float4*)a0c = *(const float4*)(av + h * 64 + wv * 16 + kq * 4);
    *(float4*)a1c = *(const float4*)(av + 256 + h * 64 + wv * 16 + kq * 4);
    #pragma unroll
    for (int nt = 0; nt < 4; ++nt) {
        int node = n0 + nt * 16 + lr;
        int b = node >> nLog;
        int j = node & (nN - 1);
        float p0 = 0.f, p1 = 0.f;
        #pragma unroll
        for (int i = 0; i < 4; ++i) {
            int d = d0 + wv * 16 + kq * 4 + i;
            bf16 vb = f2bf(acc[nt][i]);
            hgT[((long)(b * 256 + d) << nLog) + j] = vb;
            float vr = bf2f(vb);
            p0 += vr * a0c[i];
            p1 += vr * a1c[i];
        }
        p0 += __shfl_xor(p0, 16, 64); p0 += __shfl_xor(p0, 32, 64);
        p1 += __shfl_xor(p1, 16, 64); p1 += __shfl_xor(p1, 32, 64);
        if (kq == 0) { sred[wv][0][nt * 16 + lr] = p0; sred[wv][1][nt * 16 + lr] = p1; }
    }
    __syncthreads();
    if (t < 64) {
        float s0 = sred[0][0][t] + sred[1][0][t] + sred[2][0][t] + sred[3][0][t];
        float s1 = sred[0][1][t] + sred[1][1][t] + sred[2][1][t] + sred[3][1][t];
        int node = n0 + t;
        src[(long)node * 4 + h] = s0;
        dst[(long)node * 4 + h] = s1;
        float m = s1;
        #pragma unroll
        for (int o = 32; o; o >>= 1) m = fmaxf(m, __shfl_xor(m, o, 64));
        if (t == 0) atomicMax(&mx[(n0 >> nLog) * 4 + h], encf(m));
    }
}

// combined main+det GAT aggregation, round 13:
// block = (b, head, 128-row slice); 768 blocks; 4 waves, 32 rows/wave (mt=2).
// Panel strips LDS-staged with COALESCED global reads; fragments from LDS.
__global__ __launch_bounds__(256) void k_gatagg4(
    const bf16* __restrict__ hgTm, const unsigned long long* __restrict__ adjmM,
    const float4* __restrict__ srcM, const unsigned* __restrict__ mxM,
    const float4* __restrict__ dstM, const float* __restrict__ resM, bf16* __restrict__ outM,
    const bf16* __restrict__ hgTd, const unsigned long long* __restrict__ adjmD,
    const float4* __restrict__ srcD, const unsigned* __restrict__ mxD,
    const float4* __restrict__ dstD, const float* __restrict__ resD, bf16* __restrict__ outD)
{
    const float L2E = 1.44269504f;
    __shared__ float dstT[1024];
    __shared__ unsigned adjW[128][33];
    __shared__ bf16 pan[2][64][40];
    int bid = (blockIdx.x & 7) * 96 + (blockIdx.x >> 3);
    const bf16* hgT; const unsigned long long* adjm; const float4* srcv;
    const unsigned* mxp; const float4* dstv; const float* res; bf16* outb;
    int nN, b, h, i0;
    if (bid < 512) {
        hgT = hgTm; adjm = adjmM; srcv = srcM; mxp = mxM; dstv = dstM; res = resM; outb = outM;
        nN = 1024; b = bid >> 5; int r = bid & 31; h = r >> 3; i0 = (r & 7) << 7;
    } else {
        int b2 = bid - 512;
        hgT = hgTd; adjm = adjmD; srcv = srcD; mxp = mxD; dstv = dstD; res = resD; outb = outD;
        nN = 512; b = b2 >> 4; int r = b2 & 15; h = r >> 2; i0 = (r & 3) << 7;
    }
    const int t = threadIdx.x;
    const int nW = nN >> 5;                 // 32-bit words per adj row
    const int sh = (nN == 1024) ? 5 : 4;
    for (int j = t; j < nN; j += 256)
        dstT[j] = ((const float*)(dstv + (long)b * nN + j))[h] * L2E;
    {
        const unsigned* adj32 = (const unsigned*)(adjm + (long)(b * nN + i0) * (nN >> 6));
        for (int idx = t; idx < (nW << 7); idx += 256) {
            int r = idx >> sh, c = idx & (nW - 1);
            adjW[r][c] = adj32[(long)r * nW + c];
        }
    }
    const int lane = t & 63, wv = t >> 6, lr = lane & 15, kq = lane >> 4;
    const int ri = i0 + wv * 32;
    const float mdh = decf(mxp[b * 4 + h]) * L2E;
    float u[2], w[2], psum[2] = {0.f, 0.f};
    #pragma unroll
    for (int mt = 0; mt < 2; ++mt) {
        int row = ri + mt * 16 + lr;
        float s = ((const float*)(srcv + (long)b * nN + row))[h] * L2E;
        float tmp = s + mdh;
        float m = fmaxf(tmp, 0.2f * tmp);
        u[mt] = s - m;
        w[mt] = fmaf(0.2f, s, -m);
    }
    f32x4 acc[2][4] = {};
    const bf16* hb = hgT + ((long)b * 256 + h * 64) * nN;
    const int pdim = t >> 3, pch = t & 7;       // staging: dim pdim(+32), 16B chunk pch
    for (int s0 = 0; s0 < nN; s0 += 64) {
        __syncthreads();
        #pragma unroll
        for (int p = 0; p < 2; ++p) {
            int dim = pdim + p * 32;
            *(uint4*)&pan[pch >> 2][dim][(pch & 3) * 8] =
                *(const uint4*)(hb + (long)dim * nN + s0 + pch * 8);
        }
        __syncthreads();
        #pragma unroll
        for (int hf = 0; hf < 2; ++hf) {
            int j0 = s0 + hf * 32;
            bf16x8 bfr[4];
            #pragma unroll
            for (int nt = 0; nt < 4; ++nt)
                bfr[nt] = *(const bf16x8*)&pan[hf][nt * 16 + lr][kq * 8];
            float4 d0 = *(const float4*)&dstT[j0 + kq * 8];
            float4 d1 = *(const float4*)&dstT[j0 + kq * 8 + 4];
            float dv[8] = {d0.x, d0.y, d0.z, d0.w, d1.x, d1.y, d1.z, d1.w};
            #pragma unroll
            for (int mt = 0; mt < 2; ++mt) {
                unsigned byte = (adjW[wv * 32 + mt * 16 + lr][j0 >> 5] >> (kq * 8)) & 0xffu;
                bf16x8 af;
                float ps = 0.f;
                #pragma unroll
                for (int jj = 0; jj < 8; ++jj) {
                    float x = fmaxf(u[mt] + dv[jj], fmaf(0.2f, dv[jj], w[mt]));
                    float p = exp2f(x);
                    p = (byte & (1u << jj)) ? p : 0.f;
                    af[jj] = f2bf(p);
                    ps += p;
                }
                psum[mt] += ps;
                #pragma unroll
                for (int nt = 0; nt < 4; ++nt)
                    acc[mt][nt] = __builtin_amdgcn_mfma_f32_16x16x32_bf16(af, bfr[nt], acc[mt][nt], 0, 0, 0);
            }
        }
    }
    float stot[2];
    #pragma unroll
    for (int mt = 0; mt < 2; ++mt) {
        float v = psum[mt];
        v += __shfl_xor(v, 16, 64);
        v += __shfl_xor(v, 32, 64);
        stot[mt] = v;
    }
    #pragma unroll
    for (int mt = 0; mt < 2; ++mt) {
        #pragma unroll
        for (int ii = 0; ii < 4; ++ii) {
            int i = ri + mt * 16 + kq * 4 + ii;
            long bi = (long)b * nN + i;
            float sv = __shfl(stot[mt], kq * 4 + ii, 64);
            float rs = 1.f / fmaxf(sv, 1e-30f);
            #pragma unroll
            for (int nt = 0; nt < 4; ++nt) {
                int col = h * 64 + nt * 16 + lr;
                float a = acc[mt][nt][ii] * rs;
                float e = a > 0.f ? a : expm1f(a);
                float vv = 0.5f * e + 0.5f * res[(long)b * 262144 + (long)i * 256 + col];
                outb[bi * 256 + col] = f2bf(vv);
            }
        }
    }
}

// ---------------------------------------------------------------------------
extern "C" void kernel_launch(void* const* d_in, const int* in_sizes, int n_in,
                              void* d_out, int out_size, void* d_ws, size_t ws_size,
                              hipStream_t stream)
{
    (void)in_sizes; (void)n_in; (void)out_size; (void)ws_size;
    const float* tracks = (const float*)d_in[0];
    const float* dets   = (const float*)d_in[1];
    const int*  tmarks = (const int*)d_in[2];
    const int*  dmarks = (const int*)d_in[3];
    const float* W1   = (const float*)d_in[4];
    const float* b1   = (const float*)d_in[5];
    const float* W2   = (const float*)d_in[6];
    const float* b2   = (const float*)d_in[7];
    const float* Wqkv = (const float*)d_in[8];
    const float* Wo   = (const float*)d_in[9];
    const float* eff1 = (const float*)d_in[10];
    const float* eff2 = (const float*)d_in[11];
    const float* gatW = (const float*)d_in[12];
    const float* gatA = (const float*)d_in[13];
    const float* dgatW = (const float*)d_in[14];
    const float* dgatA = (const float*)d_in[15];
    const float* clsWq = (const float*)d_in[16];
    const float* clsWk = (const float*)d_in[17];
    float* out = (float*)d_out;

    char* wsb = (char*)d_ws;
    size_t off = 0;
    auto take = [&](size_t bytes) -> char* {
        char* p = wsb + off;
        off += (bytes + 255) & ~(size_t)255;
        return p;
    };
    char* R_emb  = take(37748736);   // x20(+0), h2_b(+8388608); det GAT bufs(+16M..)
    char* R_r0   = take(8388608);    // emb_r0_f
    char* R_hln  = take(33554432);   // hln; later f1_b
    char* R_v    = take(33554432);   // y main(+0) / det(+8388608)
    char* R_gat  = take(25165824);   // hgT_m(+0), xga_m(+8388608), xgb_m(+16777216)
    char* R_q    = take(4194304);    // q_b
    char* R_o0   = take(4194304);    // o0_b
    char* R_f0f  = take(16777216);   // feat0_f
    char* R_f0b  = take(8388608);    // feat0_b
    char* R_demb = take(4194304);    // demb_b
    float4* nodes = (float4*)take(262144);
    float4* src4  = (float4*)take(262144);
    float4* dst4  = (float4*)take(262144);
    unsigned* maxd_all = (unsigned*)take(1024);   // 4 layers x 16 b x 4 h
    unsigned long long* adjm_main = (unsigned long long*)take(2097152);
    unsigned long long* adjm_det  = (unsigned long long*)take(524288);
    bf16* wbuf = (bf16*)take(3014656);   // transposed bf16 weights + Wc
    float4* srcd4 = (float4*)take(131072);
    float4* dstd4 = (float4*)take(131072);

    float* emb_r0_f = (float*)R_r0;
    bf16*  hln      = (bf16*)R_hln;
    bf16*  kv_b     = (bf16*)d_out;         // 67MB scratch in d_out; dead before logits
    bf16*  q_b      = (bf16*)R_q;
    bf16*  o0_b     = (bf16*)R_o0;
    float* x20      = (float*)R_emb;
    bf16*  h2_b     = (bf16*)(R_emb + 8388608);
    bf16*  f1_b     = (bf16*)R_hln;
    float* feat0_f  = (float*)R_f0f;
    bf16*  feat0_b  = (bf16*)R_f0b;
    bf16*  demb_b   = (bf16*)R_demb;
    bf16*  hgT_m    = (bf16*)R_gat;
    bf16*  xga_m    = (bf16*)(R_gat + 8388608);
    bf16*  xgb_m    = (bf16*)(R_gat + 16777216);
    bf16*  hgT_d    = (bf16*)(R_emb + 16777216);   // x20/h2 dead once GAT starts
    bf16*  xga_d    = (bf16*)(R_emb + 20971520);
    bf16*  xgb_d    = (bf16*)(R_emb + 25165824);
    bf16*  y_m      = (bf16*)R_v;
    bf16*  y_d      = (bf16*)(R_v + 8388608);

    // transposed-weight table (+ plain cls copies for Wc)
    bf16* W2T    = wbuf + 0;
    bf16* WqkvT  = wbuf + 65536;
    bf16* WoT    = wbuf + 262144;
    bf16* eff1T  = wbuf + 327680;
    bf16* eff2T  = wbuf + 589824;
    bf16* gatW0T = wbuf + 851968;
    bf16* gatW1T = wbuf + 917504;
    bf16* dgatW0T= wbuf + 983040;
    bf16* dgatW1T= wbuf + 1048576;
    // plain copies: Wq0 @1114112, Wk0 @1179648, Wq1 @1245184, Wk1 @1310720
    bf16* WcT0   = wbuf + 1376256;
    bf16* WcT1   = wbuf + 1441792;
    PrepTab tab;
    tab.e[0]  = { W2,             0,       256,  256,  0,    1 };
    tab.e[1]  = { Wqkv,           65536,   256,  768,  64,   1 };
    tab.e[2]  = { Wo,             262144,  256,  256,  256,  1 };
    tab.e[3]  = { eff1,           327680,  256,  1024, 320,  1 };
    tab.e[4]  = { eff2,           589824,  1024, 256,  576,  1 };
    tab.e[5]  = { gatW,           851968,  256,  256,  832,  1 };
    tab.e[6]  = { gatW + 65536,   917504,  256,  256,  896,  1 };
    tab.e[7]  = { dgatW,          983040,  256,  256,  960,  1 };
    tab.e[8]  = { dgatW + 65536,  1048576, 256,  256,  1024, 1 };
    tab.e[9]  = { clsWq,          1114112, 256,  256,  1088, 0 };
    tab.e[10] = { clsWk,          1179648, 256,  256,  1152, 0 };
    tab.e[11] = { clsWq + 65536,  1245184, 256,  256,  1216, 0 };
    tab.e[12] = { clsWk + 65536,  1310720, 256,  256,  1280, 0 };

    // prep + graph + embeddings (+fused LN for track rows)
    k_prep<<<1344, 256, 0, stream>>>(tab, wbuf);
    k_wcomb<<<32, 256, 0, stream>>>(wbuf);
    k_nodes<<<64, 256, 0, stream>>>(tracks, dets, tmarks, dmarks, nodes, maxd_all);
    k_adjmask<<<768, 256, 0, stream>>>(nodes, adjm_main, adjm_det);
    k_featgemm<<<1152, 256, 0, stream>>>(tracks, dets, W1, b1, W2T, b2,
        hln, emb_r0_f, feat0_f, feat0_b, demb_b);

    // encoder (only r=0 row needed downstream of attention)
    k_kvq<<<2176, 256, 0, stream>>>(hln, WqkvT, kv_b, q_b);
    k_attn<<<8192, 256, 0, stream>>>(q_b, kv_b, o0_b);
    k_addres_ln<<<128, 256, 0, stream>>>(o0_b, WoT, emb_r0_f, x20, h2_b);
    k_gemm128_bf16<<<dim3(8, 64, 1), 256, 0, stream>>>(h2_b, 256, eff1T, 256, f1_b, 1024, 256, 1);
    k_gemm_pred<<<dim3(4, 128, 1), 256, 0, stream>>>(f1_b, 1024, eff2T, 1024, emb_r0_f, x20, feat0_f, feat0_b, 1024);

    // GAT layer 1 (main + det combined)
    k_gemmT_src<<<1536, 256, 0, stream>>>(
        gatW0T, feat0_b, hgT_m, gatA, (float*)src4, (float*)dst4, maxd_all,
        dgatW0T, demb_b, hgT_d, dgatA, (float*)srcd4, (float*)dstd4, maxd_all + 128);
    k_gatagg4<<<768, 256, 0, stream>>>(
        hgT_m, adjm_main, src4, maxd_all, dst4, feat0_f, xga_m,
        hgT_d, adjm_det, srcd4, maxd_all + 128, dstd4, feat0_f + 131072, xga_d);
    // GAT layer 2 (main + det combined)
    k_gemmT_src<<<1536, 256, 0, stream>>>(
        gatW1T, xga_m, hgT_m, gatA + 512, (float*)src4, (float*)dst4, maxd_all + 64,
        dgatW1T, xga_d, hgT_d, dgatA + 512, (float*)srcd4, (float*)dstd4, maxd_all + 192);
    k_gatagg4<<<768, 256, 0, stream>>>(
        hgT_m, adjm_main, src4, maxd_all + 64, dst4, feat0_f, xgb_m,
        hgT_d, adjm_det, srcd4, maxd_all + 192, dstd4, feat0_f + 131072, xgb_d);

    // y = x @ Wc, then logits = y @ x^T (main + det combined)
    k_y<<<1536, 256, 0, stream>>>(xgb_m, WcT0, y_m, xgb_d, WcT1, y_d);
    k_logits<<<1280, 256, 0, stream>>>(y_m, xgb_m, y_d, xgb_d, adjm_main, adjm_det,
        out, out + 20971520L);
}

// Round 8
// 476.809 us; speedup vs baseline: 1.1906x; 1.0506x over previous
//
#include <hip/hip_runtime.h>
#include <math.h>

// ScatterNet — round 14:
// - k_gatagg5: r5-proven shape (768 blocks, 128 rows, mt=2, gather panel reads)
//   + software-pipelined double-buffered gathers (static bfA/bfB),
//   + raw v_exp_f32 (__builtin_amdgcn_exp2f, L2E-prescaled) with pre-exp mask,
//   + v_cvt_pk_bf16_f32 packing (2 elems/instr), fast elu epilogue.
// - everything else as round 11 (best 494us config).

typedef __bf16 bf16;
typedef __bf16 bf16x8 __attribute__((ext_vector_type(8)));
typedef __bf16 bf16x4 __attribute__((ext_vector_type(4)));
typedef float f32x4 __attribute__((ext_vector_type(4)));

__device__ __forceinline__ float bf2f(bf16 x) { return (float)x; }
__device__ __forceinline__ bf16 f2bf(float x) { return (bf16)x; }

#if __has_builtin(__builtin_amdgcn_exp2f)
#define EXP2(x) __builtin_amdgcn_exp2f(x)
#else
#define EXP2(x) exp2f(x)
#endif

__device__ __forceinline__ unsigned cvt_pk_bf16(float lo, float hi) {
    unsigned r;
    asm("v_cvt_pk_bf16_f32 %0, %1, %2" : "=v"(r) : "v"(lo), "v"(hi));
    return r;
}

// monotone float<->uint for atomicMax on signed floats
__device__ __forceinline__ unsigned encf(float f) {
    unsigned u = __float_as_uint(f);
    return (u & 0x80000000u) ? ~u : (u | 0x80000000u);
}
__device__ __forceinline__ float decf(unsigned u) {
    return (u & 0x80000000u) ? __uint_as_float(u & 0x7fffffffu)
                             : __uint_as_float(~u);
}

// ---------------------------------------------------------------------------
// Weight prep: fp32 [R][C] -> bf16; trans=1: [C][R], trans=0: [R][C] copy.
// ---------------------------------------------------------------------------
struct PrepEnt { const float* src; long dofs; int R; int C; int tstart; int trans; };
struct PrepTab { PrepEnt e[13]; };

__global__ __launch_bounds__(256) void k_prep(PrepTab tab, bf16* __restrict__ dst)
{
    __shared__ float tile[32][33];
    const int tid = blockIdx.x;
    int k = 0;
    #pragma unroll
    for (int q = 1; q < 13; ++q) if (tid >= tab.e[q].tstart) k = q;
    PrepEnt E = tab.e[k];
    const int local = tid - E.tstart;
    const int cT = E.C >> 5;
    const int tr = local / cT, tc = local - tr * cT;
    const int r0 = tr << 5, c0 = tc << 5;
    const int t = threadIdx.x;
    {
        int r = t >> 3, cq = (t & 7) * 4;
        *(float4*)&tile[r][cq] = *(const float4*)(E.src + (long)(r0 + r) * E.C + c0 + cq);
    }
    __syncthreads();
    if (E.trans) {
        int c = t >> 3, rq = (t & 7) * 4;
        bf16x4 o;
        o[0] = f2bf(tile[rq + 0][c]); o[1] = f2bf(tile[rq + 1][c]);
        o[2] = f2bf(tile[rq + 2][c]); o[3] = f2bf(tile[rq + 3][c]);
        *(bf16x4*)(dst + E.dofs + (long)(c0 + c) * E.R + r0 + rq) = o;
    } else {
        int r = t >> 3, cq = (t & 7) * 4;
        bf16x4 o;
        o[0] = f2bf(tile[r][cq + 0]); o[1] = f2bf(tile[r][cq + 1]);
        o[2] = f2bf(tile[r][cq + 2]); o[3] = f2bf(tile[r][cq + 3]);
        *(bf16x4*)(dst + E.dofs + (long)(r0 + r) * E.C + c0 + cq) = o;
    }
}

// ---------------------------------------------------------------------------
// 64x64 MFMA GEMM core. D: row = m0 + wv*16 + kq*4 + i, col = n0 + nt*16 + lr.
// ---------------------------------------------------------------------------
__device__ __forceinline__ void gemm_bt_mn(const bf16* __restrict__ A, int lda,
                                           const bf16* __restrict__ BT, int ldb,
                                           int K, int m0, int n0, f32x4 acc[4])
{
    __shared__ bf16 As[64][40];
    __shared__ bf16 Bs[64][40];
    const int t = threadIdx.x;
    const int lane = t & 63, wv = t >> 6, lr = lane & 15, kq = lane >> 4;
    const int arow = t >> 2, acol = (t & 3) * 8;
    for (int k0 = 0; k0 < K; k0 += 32) {
        __syncthreads();
        *(uint4*)&As[arow][acol] = *(const uint4*)(A + (long)(m0 + arow) * lda + k0 + acol);
        *(uint4*)&Bs[arow][acol] = *(const uint4*)(BT + (long)(n0 + arow) * ldb + k0 + acol);
        __syncthreads();
        bf16x8 af = *(const bf16x8*)&As[wv * 16 + lr][kq * 8];
        #pragma unroll
        for (int nt = 0; nt < 4; ++nt) {
            bf16x8 bfr = *(const bf16x8*)&Bs[nt * 16 + lr][kq * 8];
            acc[nt] = __builtin_amdgcn_mfma_f32_16x16x32_bf16(af, bfr, acc[nt], 0, 0, 0);
        }
    }
}

__device__ __forceinline__ void gemm_bt(const bf16* __restrict__ A, int lda,
                                        const bf16* __restrict__ BT, int ldb,
                                        int K, f32x4 acc[4])
{
    gemm_bt_mn(A, lda, BT, ldb, K, blockIdx.y * 64, blockIdx.x * 64, acc);
}

// ---------------------------------------------------------------------------
// 128x128 MFMA GEMM core (BK=32), used by kvq / eff1.
// ---------------------------------------------------------------------------
__device__ __forceinline__ void gemm128_core(const bf16* __restrict__ A, int lda,
                                             const bf16* __restrict__ BT, int ldb,
                                             int m0, int n0, int K, f32x4 acc[2][8])
{
    __shared__ bf16 As[128][40];
    __shared__ bf16 Bs[128][40];
    const int t = threadIdx.x;
    const int lane = t & 63, wv = t >> 6, lr = lane & 15, kq = lane >> 4;
    const int srow = t >> 1, scol = (t & 1) * 16;
    for (int k0 = 0; k0 < K; k0 += 32) {
        __syncthreads();
        {
            const bf16* ap = A + (long)(m0 + srow) * lda + k0 + scol;
            *(uint4*)&As[srow][scol] = *(const uint4*)ap;
            *(uint4*)&As[srow][scol + 8] = *(const uint4*)(ap + 8);
            const bf16* bp = BT + (long)(n0 + srow) * ldb + k0 + scol;
            *(uint4*)&Bs[srow][scol] = *(const uint4*)bp;
            *(uint4*)&Bs[srow][scol + 8] = *(const uint4*)(bp + 8);
        }
        __syncthreads();
        bf16x8 af[2];
        af[0] = *(const bf16x8*)&As[wv * 32 + lr][kq * 8];
        af[1] = *(const bf16x8*)&As[wv * 32 + 16 + lr][kq * 8];
        #pragma unroll
        for (int nt = 0; nt < 8; ++nt) {
            bf16x8 bfr = *(const bf16x8*)&Bs[nt * 16 + lr][kq * 8];
            acc[0][nt] = __builtin_amdgcn_mfma_f32_16x16x32_bf16(af[0], bfr, acc[0][nt], 0, 0, 0);
            acc[1][nt] = __builtin_amdgcn_mfma_f32_16x16x32_bf16(af[1], bfr, acc[1][nt], 0, 0, 0);
        }
    }
}

// eff1 GEMM (relu)
__global__ __launch_bounds__(256) void k_gemm128_bf16(
    const bf16* __restrict__ A, int lda,
    const bf16* __restrict__ BT, int ldb,
    bf16* __restrict__ out, int ldo, int K, int relu)
{
    f32x4 acc[2][8] = {};
    const int m0 = blockIdx.y * 128, n0 = blockIdx.x * 128;
    gemm128_core(A, lda, BT, ldb, m0, n0, K, acc);
    const int lane = threadIdx.x & 63, wv = threadIdx.x >> 6;
    const int lr = lane & 15, kq = lane >> 4;
    #pragma unroll
    for (int mt = 0; mt < 2; ++mt) {
        #pragma unroll
        for (int nt = 0; nt < 8; ++nt) {
            int col = n0 + nt * 16 + lr;
            #pragma unroll
            for (int i = 0; i < 4; ++i) {
                int row = m0 + wv * 32 + mt * 16 + kq * 4 + i;
                float v = acc[mt][nt][i];
                if (relu) v = fmaxf(v, 0.f);
                out[(long)row * ldo + col] = f2bf(v);
            }
        }
    }
}

// combined KV + q projection (one launch), XCD-chunked swizzle
__global__ __launch_bounds__(256) void k_kvq(
    const bf16* __restrict__ hln, const bf16* __restrict__ WqkvT,
    bf16* __restrict__ kv, bf16* __restrict__ q)
{
    const int wg = (blockIdx.x & 7) * 272 + (blockIdx.x >> 3);
    const bf16* A; const bf16* BT; bf16* out;
    int lda, ldo, m0, n0;
    if (wg < 2048) {           // KV: 65536 rows x 512 cols
        A = hln; lda = 256; BT = WqkvT + 65536;
        m0 = (wg >> 2) * 128; n0 = (wg & 3) * 128;
        out = kv; ldo = 512;
    } else {                    // q: 8192 rows (stride-8 rows of hln) x 256 cols
        int t2 = wg - 2048;
        A = hln; lda = 2048; BT = WqkvT;
        m0 = (t2 >> 1) * 128; n0 = (t2 & 1) * 128;
        out = q; ldo = 256;
    }
    f32x4 acc[2][8] = {};
    gemm128_core(A, lda, BT, 256, m0, n0, 256, acc);
    const int lane = threadIdx.x & 63, wv = threadIdx.x >> 6;
    const int lr = lane & 15, kq = lane >> 4;
    #pragma unroll
    for (int mt = 0; mt < 2; ++mt) {
        #pragma unroll
        for (int nt = 0; nt < 8; ++nt) {
            int col = n0 + nt * 16 + lr;
            #pragma unroll
            for (int i = 0; i < 4; ++i) {
                int row = m0 + wv * 32 + mt * 16 + kq * 4 + i;
                out[(long)row * ldo + col] = f2bf(acc[mt][nt][i]);
            }
        }
    }
}

// Wc^T = Wk @ Wq^T (bf16), per cls head. 32 blocks.
__global__ __launch_bounds__(256) void k_wcomb(bf16* __restrict__ wb)
{
    const int bid = blockIdx.x;
    const int head = bid >> 4, r = bid & 15;
    const bf16* A  = wb + 1179648 + head * 131072;   // Wk plain
    const bf16* BT = wb + 1114112 + head * 131072;   // Wq plain
    bf16* out = wb + 1376256 + head * 65536;         // WcT
    const int m0 = (r >> 2) * 64, n0 = (r & 3) * 64;
    f32x4 acc[4] = {};
    gemm_bt_mn(A, 256, BT, 256, 256, m0, n0, acc);
    const int lane = threadIdx.x & 63, wv = threadIdx.x >> 6;
    const int lr = lane & 15, kq = lane >> 4;
    #pragma unroll
    for (int nt = 0; nt < 4; ++nt) {
        int col = n0 + nt * 16 + lr;
        #pragma unroll
        for (int i = 0; i < 4; ++i) {
            int row = m0 + wv * 16 + kq * 4 + i;
            out[(long)row * 256 + col] = f2bf(acc[nt][i]);
        }
    }
}

// y = x @ Wc (main + det combined), XCD-chunked swizzle
__global__ __launch_bounds__(256) void k_y(
    const bf16* __restrict__ xm, const bf16* __restrict__ WcT0, bf16* __restrict__ ym,
    const bf16* __restrict__ xd, const bf16* __restrict__ WcT1, bf16* __restrict__ yd)
{
    const int wg = (blockIdx.x & 7) * 192 + (blockIdx.x >> 3);
    int by = wg >> 2;
    const int bx = wg & 3;
    const bf16 *A, *BT; bf16* out;
    if (by < 256) { A = xm; BT = WcT0; out = ym; }
    else          { by -= 256; A = xd; BT = WcT1; out = yd; }
    f32x4 acc[4] = {};
    const int m0 = by * 64, n0 = bx * 64;
    gemm_bt_mn(A, 256, BT, 256, 256, m0, n0, acc);
    const int lane = threadIdx.x & 63, wv = threadIdx.x >> 6;
    const int lr = lane & 15, kq = lane >> 4;
    #pragma unroll
    for (int nt = 0; nt < 4; ++nt) {
        int col = n0 + nt * 16 + lr;
        #pragma unroll
        for (int i = 0; i < 4; ++i) {
            int row = m0 + wv * 16 + kq * 4 + i;
            out[(long)row * 256 + col] = f2bf(acc[nt][i]);
        }
    }
}

// logits = y @ x^T, sigmoid(/16)*adj epilogue. BK=64 core, XCD swizzle.
__global__ __launch_bounds__(256) void k_logits(
    const bf16* __restrict__ ym, const bf16* __restrict__ xm,
    const bf16* __restrict__ yd, const bf16* __restrict__ xd,
    const unsigned long long* __restrict__ adjmM,
    const unsigned long long* __restrict__ adjmD,
    float* __restrict__ out, float* __restrict__ asso)
{
    const int wg = (blockIdx.x & 7) * 160 + (blockIdx.x >> 3);
    const bf16 *A, *BT; float* ob; const unsigned long long* adjm;
    int ldo, nN, nC, flags, m0, n0, z;
    if (wg < 1024) {
        z = wg >> 6; int r = wg & 63;
        m0 = (r >> 3) * 128; n0 = (r & 7) * 128;
        A = ym + (long)z * 262144; BT = xm + (long)z * 262144;
        ob = out + (long)z * 1048576; ldo = 1024;
        adjm = adjmM; nN = 1024; nC = 16; flags = 1;
    } else {
        int t2 = wg - 1024;
        z = t2 >> 4; int r = t2 & 15;
        m0 = (r >> 2) * 128; n0 = (r & 3) * 128;
        A = yd + (long)z * 131072; BT = xd + (long)z * 131072;
        ob = out + 16777216 + (long)z * 262144; ldo = 512;
        adjm = adjmD; nN = 512; nC = 8; flags = 2;
    }
    const int t = threadIdx.x;
    const int lane = t & 63, wv = t >> 6, lr = lane & 15, kq = lane >> 4;
    f32x4 acc[2][8] = {};
    {
        __shared__ bf16 As[128][72];
        __shared__ bf16 Bs[128][72];
        const int srow4 = t >> 3, scol8 = (t & 7) * 8;
        for (int k0 = 0; k0 < 256; k0 += 64) {
            __syncthreads();
            #pragma unroll
            for (int p = 0; p < 4; ++p) {
                int row = p * 32 + srow4;
                *(uint4*)&As[row][scol8] = *(const uint4*)(A + (long)(m0 + row) * 256 + k0 + scol8);
                *(uint4*)&Bs[row][scol8] = *(const uint4*)(BT + (long)(n0 + row) * 256 + k0 + scol8);
            }
            __syncthreads();
            #pragma unroll
            for (int ks = 0; ks < 64; ks += 32) {
                bf16x8 af[2];
                af[0] = *(const bf16x8*)&As[wv * 32 + lr][kq * 8 + ks];
                af[1] = *(const bf16x8*)&As[wv * 32 + 16 + lr][kq * 8 + ks];
                #pragma unroll
                for (int nt = 0; nt < 8; ++nt) {
                    bf16x8 bfr = *(const bf16x8*)&Bs[nt * 16 + lr][kq * 8 + ks];
                    acc[0][nt] = __builtin_amdgcn_mfma_f32_16x16x32_bf16(af[0], bfr, acc[0][nt], 0, 0, 0);
                    acc[1][nt] = __builtin_amdgcn_mfma_f32_16x16x32_bf16(af[1], bfr, acc[1][nt], 0, 0, 0);
                }
            }
        }
    }
    #pragma unroll
    for (int mt = 0; mt < 2; ++mt) {
        #pragma unroll
        for (int i = 0; i < 4; ++i) {
            int row = m0 + wv * 32 + mt * 16 + kq * 4 + i;
            unsigned long long w0 = adjm[((long)z * nN + row) * nC + (n0 >> 6)];
            unsigned long long w1 = adjm[((long)z * nN + row) * nC + (n0 >> 6) + 1];
            #pragma unroll
            for (int nt = 0; nt < 8; ++nt) {
                int col = n0 + nt * 16 + lr;
                int bp = nt * 16 + lr;
                bool adj = (bp < 64) ? ((w0 >> bp) & 1ull) : ((w1 >> (bp - 64)) & 1ull);
                if ((flags & 2) && row == col) adj = false;
                float v = 0.f;
                if (adj) v = 1.f / (1.f + __expf(-acc[mt][nt][i] * 0.0625f));
                ob[(long)row * ldo + col] = v;
                if ((flags & 1) && row < 512 && col >= 512)
                    asso[(long)z * 262144 + (long)row * 512 + (col - 512)] = v;
            }
        }
    }
}

// predicted = tr_emb0 + 0.9*(x2_0 + ff2_out); scattered to feat0[b*1024+m]
__global__ __launch_bounds__(256) void k_gemm_pred(
    const bf16* __restrict__ A, int lda,
    const bf16* __restrict__ BT, int ldb,
    const float* __restrict__ res1, const float* __restrict__ res2,
    float* __restrict__ outf, bf16* __restrict__ outb, int K)
{
    f32x4 acc[4] = {};
    gemm_bt(A, lda, BT, ldb, K, acc);
    const int lane = threadIdx.x & 63, wv = threadIdx.x >> 6;
    const int lr = lane & 15, kq = lane >> 4;
    const int m0 = blockIdx.y * 64, n0 = blockIdx.x * 64;
    #pragma unroll
    for (int nt = 0; nt < 4; ++nt) {
        int col = n0 + nt * 16 + lr;
        #pragma unroll
        for (int i = 0; i < 4; ++i) {
            int row = m0 + wv * 16 + kq * 4 + i;     // b*512 + m
            float v = res1[(long)row * 256 + col]
                    + 0.9f * (res2[(long)row * 256 + col] + acc[nt][i]);
            long drow = (long)row + ((row >> 9) << 9);   // b*1024 + m
            long o = drow * 256 + col;
            outf[o] = v;
            outb[o] = f2bf(v);
        }
    }
}

// ---------------------------------------------------------------------------
// fused feat MLP + LayerNorm epilogue (track rows). 64 rows x 256 cols/block.
// ---------------------------------------------------------------------------
__global__ __launch_bounds__(256) void k_featgemm(
    const float* __restrict__ tracks, const float* __restrict__ dets,
    const float* __restrict__ W1, const float* __restrict__ b1,
    const bf16* __restrict__ W2T, const float* __restrict__ b2,
    bf16* __restrict__ hln, float* __restrict__ emb_r0_f,
    float* __restrict__ feat0_f, bf16* __restrict__ feat0_b,
    bf16* __restrict__ demb_b)
{
    __shared__ float xr[64][4];
    __shared__ float w1s[4][256];
    __shared__ float b1s[256];
    __shared__ bf16 As[64][40];
    __shared__ bf16 Bs[256][40];
    const int t = threadIdx.x;
    const int m0 = blockIdx.x * 64;
    if (t < 64) {
        int gr = m0 + t;
        const float* sp = (gr < 65536) ? (tracks + (long)gr * 4)
                                       : (dets + (long)(gr - 65536) * 4);
        *(float4*)&xr[t][0] = *(const float4*)sp;
    }
    w1s[0][t] = W1[t];       w1s[1][t] = W1[256 + t];
    w1s[2][t] = W1[512 + t]; w1s[3][t] = W1[768 + t];
    b1s[t] = b1[t];
    const int arow = t >> 2, acol = (t & 3) * 8;
    const int lane = t & 63, wv = t >> 6, lr = lane & 15, kq = lane >> 4;
    f32x4 acc[16] = {};
    __syncthreads();
    for (int k0 = 0; k0 < 256; k0 += 32) {
        __syncthreads();
        #pragma unroll
        for (int j = 0; j < 8; ++j) {
            int c = k0 + acol + j;
            float v = fmaf(xr[arow][0], w1s[0][c],
                      fmaf(xr[arow][1], w1s[1][c],
                      fmaf(xr[arow][2], w1s[2][c],
                      fmaf(xr[arow][3], w1s[3][c], b1s[c]))));
            v = v > 0.f ? v : (__expf(v) - 1.f);
            As[arow][acol + j] = f2bf(v);
        }
        #pragma unroll
        for (int rr = 0; rr < 4; ++rr) {
            int n = rr * 64 + (t >> 2);
            *(uint4*)&Bs[n][acol] = *(const uint4*)(W2T + (long)n * 256 + k0 + acol);
        }
        __syncthreads();
        bf16x8 af = *(const bf16x8*)&As[wv * 16 + lr][kq * 8];
        #pragma unroll
        for (int nt = 0; nt < 16; ++nt) {
            bf16x8 bfr = *(const bf16x8*)&Bs[nt * 16 + lr][kq * 8];
            acc[nt] = __builtin_amdgcn_mfma_f32_16x16x32_bf16(af, bfr, acc[nt], 0, 0, 0);
        }
    }
    if (m0 < 65536) {
        #pragma unroll
        for (int nt = 0; nt < 16; ++nt) {
            int col = nt * 16 + lr;
            float bv = b2[col];
            #pragma unroll
            for (int i = 0; i < 4; ++i) {
                int gr = m0 + wv * 16 + kq * 4 + i;
                float v = acc[nt][i] + bv;
                if ((gr & 7) == 0) emb_r0_f[(long)(gr >> 3) * 256 + col] = v;
                acc[nt][i] = bf2f(f2bf(v));   // bit-match old bf16 emb path
            }
        }
        float mean[4], rstd[4];
        #pragma unroll
        for (int i = 0; i < 4; ++i) {
            float s1 = 0.f, s2 = 0.f;
            #pragma unroll
            for (int nt = 0; nt < 16; ++nt) {
                float v = acc[nt][i];
                s1 += v; s2 += v * v;
            }
            #pragma unroll
            for (int o = 1; o < 16; o <<= 1) {
                s1 += __shfl_xor(s1, o, 64);
                s2 += __shfl_xor(s2, o, 64);
            }
            float mu = s1 * (1.f / 256.f);
            mean[i] = mu;
            rstd[i] = rsqrtf(fmaxf(s2 * (1.f / 256.f) - mu * mu, 0.f) + 1e-5f);
        }
        #pragma unroll
        for (int nt = 0; nt < 16; ++nt) {
            int col = nt * 16 + lr;
            #pragma unroll
            for (int i = 0; i < 4; ++i) {
                int gr = m0 + wv * 16 + kq * 4 + i;
                hln[(long)gr * 256 + col] = f2bf((acc[nt][i] - mean[i]) * rstd[i]);
            }
        }
    } else {
        #pragma unroll
        for (int nt = 0; nt < 16; ++nt) {
            int col = nt * 16 + lr;
            float bv = b2[col];
            #pragma unroll
            for (int i = 0; i < 4; ++i) {
                int gr = m0 + wv * 16 + kq * 4 + i;
                float v = acc[nt][i] + bv;
                int dr = gr - 65536;
                long drow = ((long)(dr >> 9) << 10) + 512 + (dr & 511);
                feat0_f[drow * 256 + col] = v;
                feat0_b[drow * 256 + col] = f2bf(v);
                demb_b[(long)dr * 256 + col] = f2bf(v);
            }
        }
    }
}

// adjacency bitmask: LDS-staged nodes, 32 rows per block.
__global__ __launch_bounds__(256) void k_adjmask(
    const float4* __restrict__ nodes,
    unsigned long long* __restrict__ adjm_main,
    unsigned long long* __restrict__ adjm_det)
{
    __shared__ float4 nds[1024];
    int bid = blockIdx.x;
    int nN, b, i0, nodeOfs;
    unsigned long long* adjm;
    if (bid < 512) { nN = 1024; b = bid >> 5; i0 = (bid & 31) << 5; nodeOfs = 0; adjm = adjm_main; }
    else { int b2 = bid - 512; nN = 512; b = b2 >> 4; i0 = (b2 & 15) << 5; nodeOfs = 512; adjm = adjm_det; }
    const float4* nb = nodes + b * 1024 + nodeOfs;
    const int t = threadIdx.x;
    for (int j = t; j < nN; j += 256) nds[j] = nb[j];
    __syncthreads();
    const int w = t >> 6, l = t & 63;
    const int nC = nN >> 6;
    for (int ii = 0; ii < 8; ++ii) {
        int i = i0 + w * 8 + ii;
        float4 ni = nds[i];
        for (int c = 0; c < nC; ++c) {
            float4 nj = nds[c * 64 + l];
            float dx = ni.x - nj.x, dy = ni.y - nj.y;
            bool adj = (dx * dx + dy * dy < 4.f) && (ni.z + nj.z < 1.f);
            unsigned long long mask = __ballot(adj);
            if (l == 0) adjm[(long)(b * nN + i) * nC + c] = mask;
        }
    }
}

// Wo-residual + LayerNorm, wide-N: 64 rows x 256 cols/block.
__global__ __launch_bounds__(256) void k_addres_ln(
    const bf16* __restrict__ A, const bf16* __restrict__ BT,
    const float* __restrict__ res1,
    float* __restrict__ x2out, bf16* __restrict__ h2)
{
    __shared__ bf16 As[64][40];
    __shared__ bf16 Bs[256][40];
    const int t = threadIdx.x;
    const int m0 = blockIdx.x * 64;
    const int arow = t >> 2, acol = (t & 3) * 8;
    const int lane = t & 63, wv = t >> 6, lr = lane & 15, kq = lane >> 4;
    f32x4 acc[16] = {};
    for (int k0 = 0; k0 < 256; k0 += 32) {
        __syncthreads();
        *(uint4*)&As[arow][acol] = *(const uint4*)(A + (long)(m0 + arow) * 256 + k0 + acol);
        #pragma unroll
        for (int rr = 0; rr < 4; ++rr) {
            int n = rr * 64 + (t >> 2);
            *(uint4*)&Bs[n][acol] = *(const uint4*)(BT + (long)n * 256 + k0 + acol);
        }
        __syncthreads();
        bf16x8 af = *(const bf16x8*)&As[wv * 16 + lr][kq * 8];
        #pragma unroll
        for (int nt = 0; nt < 16; ++nt) {
            bf16x8 bfr = *(const bf16x8*)&Bs[nt * 16 + lr][kq * 8];
            acc[nt] = __builtin_amdgcn_mfma_f32_16x16x32_bf16(af, bfr, acc[nt], 0, 0, 0);
        }
    }
    float mean[4], rstd[4];
    #pragma unroll
    for (int i = 0; i < 4; ++i) {
        int row = m0 + wv * 16 + kq * 4 + i;
        float s1 = 0.f, s2 = 0.f;
        #pragma unroll
        for (int nt = 0; nt < 16; ++nt) {
            float v = res1[(long)row * 256 + nt * 16 + lr] + acc[nt][i];
            acc[nt][i] = v;
            s1 += v; s2 += v * v;
        }
        #pragma unroll
        for (int o = 1; o < 16; o <<= 1) {
            s1 += __shfl_xor(s1, o, 64);
            s2 += __shfl_xor(s2, o, 64);
        }
        float mu = s1 * (1.f / 256.f);
        mean[i] = mu;
        rstd[i] = rsqrtf(fmaxf(s2 * (1.f / 256.f) - mu * mu, 0.f) + 1e-5f);
    }
    #pragma unroll
    for (int nt = 0; nt < 16; ++nt) {
        int col = nt * 16 + lr;
        #pragma unroll
        for (int i = 0; i < 4; ++i) {
            int row = m0 + wv * 16 + kq * 4 + i;
            float v = acc[nt][i];
            x2out[(long)row * 256 + col] = v;
            h2[(long)row * 256 + col] = f2bf((v - mean[i]) * rstd[i]);
        }
    }
}

// encoder attention, r=0 row only. kv layout: [row][512]
__global__ __launch_bounds__(256) void k_attn(
    const bf16* __restrict__ q, const bf16* __restrict__ kv,
    bf16* __restrict__ o0)
{
    const long t = blockIdx.x;
    const int h = threadIdx.x >> 6;
    const int lane = threadIdx.x & 63;
    const int s = lane >> 3;
    const int dg = lane & 7;
    const bf16* qp = q + t * 256 + h * 64 + dg * 8;
    const bf16* kp = kv + (t * 8 + s) * 512 + h * 64 + dg * 8;
    float p = 0.f;
    #pragma unroll
    for (int e = 0; e < 8; ++e) p += bf2f(qp[e]) * bf2f(kp[e]);
    p += __shfl_xor(p, 1, 64);
    p += __shfl_xor(p, 2, 64);
    p += __shfl_xor(p, 4, 64);
    float sc = p * 0.125f;
    float w[8];
    float mx = -1e30f;
    #pragma unroll
    for (int s2 = 0; s2 < 8; ++s2) { w[s2] = __shfl(sc, s2 * 8, 64); mx = fmaxf(mx, w[s2]); }
    float sum = 0.f;
    #pragma unroll
    for (int s2 = 0; s2 < 8; ++s2) { w[s2] = __expf(w[s2] - mx); sum += w[s2]; }
    float rs = 1.f / sum;
    float acc = 0.f;
    const bf16* vp = kv + (t * 8) * 512 + 256 + h * 64 + lane;
    #pragma unroll
    for (int s2 = 0; s2 < 8; ++s2) acc += w[s2] * bf2f(vp[(long)s2 * 512]);
    o0[t * 256 + h * 64 + lane] = f2bf(acc * rs);
}

__global__ __launch_bounds__(256) void k_nodes(
    const float* __restrict__ tracks, const float* __restrict__ dets,
    const int* __restrict__ tm, const int* __restrict__ dm,
    float4* __restrict__ nodes, unsigned* __restrict__ maxd_all)
{
    int idx = blockIdx.x * 256 + threadIdx.x;
    if (blockIdx.x == 0) maxd_all[threadIdx.x] = 0x007fffffu;   // enc(-inf), 4 layers x 64
    int b = idx >> 10;
    int i = idx & 1023;
    float x, y;
    int valid;
    if (i < 512) {
        long o = (long)(b * 512 + i) * 32;
        x = tracks[o]; y = tracks[o + 1];
        valid = (i < tm[b]) ? 1 : 0;
    } else {
        int n = i - 512;
        long o = (long)(b * 512 + n) * 4;
        x = dets[o]; y = dets[o + 1];
        valid = (n < dm[b]) ? 1 : 0;
    }
    nodes[idx] = make_float4(x, y, valid ? 0.f : 1e9f, 0.f);
}

// ---------------------------------------------------------------------------
// combined main+det GAT projection (transposed out) with FUSED src/dst dots.
// 1D grid, logical wg: head = wg&3, bx = wg>>2 (4 heads of one bx adjacent).
// ---------------------------------------------------------------------------
__global__ __launch_bounds__(256) void k_gemmT_src(
    const bf16* __restrict__ WTm, const bf16* __restrict__ Xm, bf16* __restrict__ hgTm,
    const float* __restrict__ avm, float* __restrict__ srcm, float* __restrict__ dstm,
    unsigned* __restrict__ mxm,
    const bf16* __restrict__ WTd, const bf16* __restrict__ Xd, bf16* __restrict__ hgTd,
    const float* __restrict__ avd, float* __restrict__ srcd, float* __restrict__ dstd,
    unsigned* __restrict__ mxd)
{
    __shared__ float sred[4][2][64];
    const int wg = (blockIdx.x & 7) * 192 + (blockIdx.x >> 3);
    const int h = wg & 3;
    int bx = wg >> 2;
    const bf16 *WT, *X; bf16* hgT; const float* av;
    float *src, *dst; unsigned* mx; int nN, nLog;
    if (bx < 256) { WT = WTm; X = Xm; hgT = hgTm; av = avm; src = srcm; dst = dstm; mx = mxm; nN = 1024; nLog = 10; }
    else { bx -= 256; WT = WTd; X = Xd; hgT = hgTd; av = avd; src = srcd; dst = dstd; mx = mxd; nN = 512; nLog = 9; }
    const int d0 = h * 64, n0 = bx * 64;
    f32x4 acc[4] = {};
    gemm_bt_mn(WT, 256, X, 256, 256, d0, n0, acc);
    const int t = threadIdx.x, lane = t & 63, wv = t >> 6, lr = lane & 15, kq = lane >> 4;
    float a0c[4], a1c[4];
    *(float4*)a0c = *(const float4*)(av + h * 64 + wv * 16 + kq * 4);
    *(float4*)a1c = *(const float4*)(av + 256 + h * 64 + wv * 16 + kq * 4);
    #pragma unroll
    for (int nt = 0; nt < 4; ++nt) {
        int node = n0 + nt * 16 + lr;
        int b = node >> nLog;
        int j = node & (nN - 1);
        float p0 = 0.f, p1 = 0.f;
        #pragma unroll
        for (int i = 0; i < 4; ++i) {
            int d = d0 + wv * 16 + kq * 4 + i;
            bf16 vb = f2bf(acc[nt][i]);
            hgT[((long)(b * 256 + d) << nLog) + j] = vb;
            float vr = bf2f(vb);
            p0 += vr * a0c[i];
            p1 += vr * a1c[i];
        }
        p0 += __shfl_xor(p0, 16, 64); p0 += __shfl_xor(p0, 32, 64);
        p1 += __shfl_xor(p1, 16, 64); p1 += __shfl_xor(p1, 32, 64);
        if (kq == 0) { sred[wv][0][nt * 16 + lr] = p0; sred[wv][1][nt * 16 + lr] = p1; }
    }
    __syncthreads();
    if (t < 64) {
        float s0 = sred[0][0][t] + sred[1][0][t] + sred[2][0][t] + sred[3][0][t];
        float s1 = sred[0][1][t] + sred[1][1][t] + sred[2][1][t] + sred[3][1][t];
        int node = n0 + t;
        src[(long)node * 4 + h] = s0;
        dst[(long)node * 4 + h] = s1;
        float m = s1;
        #pragma unroll
        for (int o = 32; o; o >>= 1) m = fmaxf(m, __shfl_xor(m, o, 64));
        if (t == 0) atomicMax(&mx[(n0 >> nLog) * 4 + h], encf(m));
    }
}

// combined main+det GAT aggregation, round 14:
// r5 shape (768 blocks, b/h/128-row slice, mt=2, gather panel) +
// double-buffered prefetch + raw v_exp + cvt_pk_bf16 pack + fast elu.
__global__ __launch_bounds__(256) void k_gatagg5(
    const bf16* __restrict__ hgTm, const unsigned long long* __restrict__ adjmM,
    const float4* __restrict__ srcM, const unsigned* __restrict__ mxM,
    const float4* __restrict__ dstM, const float* __restrict__ resM, bf16* __restrict__ outM,
    const bf16* __restrict__ hgTd, const unsigned long long* __restrict__ adjmD,
    const float4* __restrict__ srcD, const unsigned* __restrict__ mxD,
    const float4* __restrict__ dstD, const float* __restrict__ resD, bf16* __restrict__ outD)
{
    const float L2E = 1.44269504f;
    __shared__ float dstT[1024];
    __shared__ unsigned adjW[128][33];
    int bid = (blockIdx.x & 7) * 96 + (blockIdx.x >> 3);
    const bf16* hgT; const unsigned long long* adjm; const float4* srcv;
    const unsigned* mxp; const float4* dstv; const float* res; bf16* outb;
    int nN, b, h, i0;
    if (bid < 512) {
        hgT = hgTm; adjm = adjmM; srcv = srcM; mxp = mxM; dstv = dstM; res = resM; outb = outM;
        nN = 1024; b = bid >> 5; int r = bid & 31; h = r >> 3; i0 = (r & 7) << 7;
    } else {
        int b2 = bid - 512;
        hgT = hgTd; adjm = adjmD; srcv = srcD; mxp = mxD; dstv = dstD; res = resD; outb = outD;
        nN = 512; b = b2 >> 4; int r = b2 & 15; h = r >> 2; i0 = (r & 3) << 7;
    }
    const int t = threadIdx.x;
    const int nW = nN >> 5;                 // 32-bit words per adj row
    const int sh = (nN == 1024) ? 5 : 4;
    for (int j = t; j < nN; j += 256)
        dstT[j] = ((const float*)(dstv + (long)b * nN + j))[h] * L2E;
    {
        const unsigned* adj32 = (const unsigned*)(adjm + (long)(b * nN + i0) * (nN >> 6));
        for (int idx = t; idx < (nW << 7); idx += 256) {
            int r = idx >> sh, c = idx & (nW - 1);
            adjW[r][c] = adj32[(long)r * nW + c];
        }
    }
    __syncthreads();
    const int lane = t & 63, wv = t >> 6, lr = lane & 15, kq = lane >> 4;
    const int ri = i0 + wv * 32;
    const float mdh = decf(mxp[b * 4 + h]) * L2E;
    float u[2], w[2], psum[2] = {0.f, 0.f};
    #pragma unroll
    for (int mt = 0; mt < 2; ++mt) {
        int row = ri + mt * 16 + lr;
        float s = ((const float*)(srcv + (long)b * nN + row))[h] * L2E;
        float tmp = s + mdh;
        float m = fmaxf(tmp, 0.2f * tmp);
        u[mt] = s - m;
        w[mt] = fmaf(0.2f, s, -m);
    }
    f32x4 acc[2][4] = {};
    const bf16* hb = hgT + ((long)b * 256 + h * 64) * nN;
    const int nIter = nN >> 5;              // 32 or 16, always even

    bf16x8 bfA0, bfA1, bfA2, bfA3, bfB0, bfB1, bfB2, bfB3;
    #define GLOAD(dst0, dst1, dst2, dst3, J0)                                   \
        dst0 = *(const bf16x8*)(hb + (long)(0 * 16 + lr) * nN + (J0) + kq * 8); \
        dst1 = *(const bf16x8*)(hb + (long)(1 * 16 + lr) * nN + (J0) + kq * 8); \
        dst2 = *(const bf16x8*)(hb + (long)(2 * 16 + lr) * nN + (J0) + kq * 8); \
        dst3 = *(const bf16x8*)(hb + (long)(3 * 16 + lr) * nN + (J0) + kq * 8);

    auto step = [&](bf16x8 f0, bf16x8 f1, bf16x8 f2, bf16x8 f3, int j0) {
        float4 d0 = *(const float4*)&dstT[j0 + kq * 8];
        float4 d1 = *(const float4*)&dstT[j0 + kq * 8 + 4];
        float dd[8] = {d0.x, d0.y, d0.z, d0.w, d1.x, d1.y, d1.z, d1.w};
        #pragma unroll
        for (int mt = 0; mt < 2; ++mt) {
            unsigned byte = (adjW[wv * 32 + mt * 16 + lr][j0 >> 5] >> (kq * 8)) & 0xffu;
            float p[8];
            #pragma unroll
            for (int jj = 0; jj < 8; ++jj) {
                float x = fmaxf(u[mt] + dd[jj], fmaf(0.2f, dd[jj], w[mt]));
                x = (byte & (1u << jj)) ? x : -1e30f;
                p[jj] = EXP2(x);
                psum[mt] += p[jj];
            }
            union { bf16x8 v; unsigned u32[4]; } A;
            A.u32[0] = cvt_pk_bf16(p[0], p[1]);
            A.u32[1] = cvt_pk_bf16(p[2], p[3]);
            A.u32[2] = cvt_pk_bf16(p[4], p[5]);
            A.u32[3] = cvt_pk_bf16(p[6], p[7]);
            acc[mt][0] = __builtin_amdgcn_mfma_f32_16x16x32_bf16(A.v, f0, acc[mt][0], 0, 0, 0);
            acc[mt][1] = __builtin_amdgcn_mfma_f32_16x16x32_bf16(A.v, f1, acc[mt][1], 0, 0, 0);
            acc[mt][2] = __builtin_amdgcn_mfma_f32_16x16x32_bf16(A.v, f2, acc[mt][2], 0, 0, 0);
            acc[mt][3] = __builtin_amdgcn_mfma_f32_16x16x32_bf16(A.v, f3, acc[mt][3], 0, 0, 0);
        }
    };

    GLOAD(bfA0, bfA1, bfA2, bfA3, 0)
    for (int it = 0; it < nIter; it += 2) {
        int j0 = it << 5;
        GLOAD(bfB0, bfB1, bfB2, bfB3, j0 + 32)
        step(bfA0, bfA1, bfA2, bfA3, j0);
        if (it + 2 < nIter) { GLOAD(bfA0, bfA1, bfA2, bfA3, j0 + 64) }
        step(bfB0, bfB1, bfB2, bfB3, j0 + 32);
    }
    #undef GLOAD

    float stot[2];
    #pragma unroll
    for (int mt = 0; mt < 2; ++mt) {
        float v = psum[mt];
        v += __shfl_xor(v, 16, 64);
        v += __shfl_xor(v, 32, 64);
        stot[mt] = v;
    }
    #pragma unroll
    for (int mt = 0; mt < 2; ++mt) {
        #pragma unroll
        for (int ii = 0; ii < 4; ++ii) {
            int i = ri + mt * 16 + kq * 4 + ii;
            long bi = (long)b * nN + i;
            float sv = __shfl(stot[mt], kq * 4 + ii, 64);
            float rs = 1.f / fmaxf(sv, 1e-30f);
            #pragma unroll
            for (int nt = 0; nt < 4; ++nt) {
                int col = h * 64 + nt * 16 + lr;
                float a = acc[mt][nt][ii] * rs;
                float e = a > 0.f ? a : (__expf(a) - 1.f);
                float vv = 0.5f * e + 0.5f * res[(long)b * 262144 + (long)i * 256 + col];
                outb[bi * 256 + col] = f2bf(vv);
            }
        }
    }
}

// ---------------------------------------------------------------------------
extern "C" void kernel_launch(void* const* d_in, const int* in_sizes, int n_in,
                              void* d_out, int out_size, void* d_ws, size_t ws_size,
                              hipStream_t stream)
{
    (void)in_sizes; (void)n_in; (void)out_size; (void)ws_size;
    const float* tracks = (const float*)d_in[0];
    const float* dets   = (const float*)d_in[1];
    const int*  tmarks = (const int*)d_in[2];
    const int*  dmarks = (const int*)d_in[3];
    const float* W1   = (const float*)d_in[4];
    const float* b1   = (const float*)d_in[5];
    const float* W2   = (const float*)d_in[6];
    const float* b2   = (const float*)d_in[7];
    const float* Wqkv = (const float*)d_in[8];
    const float* Wo   = (const float*)d_in[9];
    const float* eff1 = (const float*)d_in[10];
    const float* eff2 = (const float*)d_in[11];
    const float* gatW = (const float*)d_in[12];
    const float* gatA = (const float*)d_in[13];
    const float* dgatW = (const float*)d_in[14];
    const float* dgatA = (const float*)d_in[15];
    const float* clsWq = (const float*)d_in[16];
    const float* clsWk = (const float*)d_in[17];
    float* out = (float*)d_out;

    char* wsb = (char*)d_ws;
    size_t off = 0;
    auto take = [&](size_t bytes) -> char* {
        char* p = wsb + off;
        off += (bytes + 255) & ~(size_t)255;
        return p;
    };
    char* R_emb  = take(37748736);   // x20(+0), h2_b(+8388608); det GAT bufs(+16M..)
    char* R_r0   = take(8388608);    // emb_r0_f
    char* R_hln  = take(33554432);   // hln; later f1_b
    char* R_v    = take(33554432);   // y main(+0) / det(+8388608)
    char* R_gat  = take(25165824);   // hgT_m(+0), xga_m(+8388608), xgb_m(+16777216)
    char* R_q    = take(4194304);    // q_b
    char* R_o0   = take(4194304);    // o0_b
    char* R_f0f  = take(16777216);   // feat0_f
    char* R_f0b  = take(8388608);    // feat0_b
    char* R_demb = take(4194304);    // demb_b
    float4* nodes = (float4*)take(262144);
    float4* src4  = (float4*)take(262144);
    float4* dst4  = (float4*)take(262144);
    unsigned* maxd_all = (unsigned*)take(1024);   // 4 layers x 16 b x 4 h
    unsigned long long* adjm_main = (unsigned long long*)take(2097152);
    unsigned long long* adjm_det  = (unsigned long long*)take(524288);
    bf16* wbuf = (bf16*)take(3014656);   // transposed bf16 weights + Wc
    float4* srcd4 = (float4*)take(131072);
    float4* dstd4 = (float4*)take(131072);

    float* emb_r0_f = (float*)R_r0;
    bf16*  hln      = (bf16*)R_hln;
    bf16*  kv_b     = (bf16*)d_out;         // 67MB scratch in d_out; dead before logits
    bf16*  q_b      = (bf16*)R_q;
    bf16*  o0_b     = (bf16*)R_o0;
    float* x20      = (float*)R_emb;
    bf16*  h2_b     = (bf16*)(R_emb + 8388608);
    bf16*  f1_b     = (bf16*)R_hln;
    float* feat0_f  = (float*)R_f0f;
    bf16*  feat0_b  = (bf16*)R_f0b;
    bf16*  demb_b   = (bf16*)R_demb;
    bf16*  hgT_m    = (bf16*)R_gat;
    bf16*  xga_m    = (bf16*)(R_gat + 8388608);
    bf16*  xgb_m    = (bf16*)(R_gat + 16777216);
    bf16*  hgT_d    = (bf16*)(R_emb + 16777216);   // x20/h2 dead once GAT starts
    bf16*  xga_d    = (bf16*)(R_emb + 20971520);
    bf16*  xgb_d    = (bf16*)(R_emb + 25165824);
    bf16*  y_m      = (bf16*)R_v;
    bf16*  y_d      = (bf16*)(R_v + 8388608);

    // transposed-weight table (+ plain cls copies for Wc)
    bf16* W2T    = wbuf + 0;
    bf16* WqkvT  = wbuf + 65536;
    bf16* WoT    = wbuf + 262144;
    bf16* eff1T  = wbuf + 327680;
    bf16* eff2T  = wbuf + 589824;
    bf16* gatW0T = wbuf + 851968;
    bf16* gatW1T = wbuf + 917504;
    bf16* dgatW0T= wbuf + 983040;
    bf16* dgatW1T= wbuf + 1048576;
    // plain copies: Wq0 @1114112, Wk0 @1179648, Wq1 @1245184, Wk1 @1310720
    bf16* WcT0   = wbuf + 1376256;
    bf16* WcT1   = wbuf + 1441792;
    PrepTab tab;
    tab.e[0]  = { W2,             0,       256,  256,  0,    1 };
    tab.e[1]  = { Wqkv,           65536,   256,  768,  64,   1 };
    tab.e[2]  = { Wo,             262144,  256,  256,  256,  1 };
    tab.e[3]  = { eff1,           327680,  256,  1024, 320,  1 };
    tab.e[4]  = { eff2,           589824,  1024, 256,  576,  1 };
    tab.e[5]  = { gatW,           851968,  256,  256,  832,  1 };
    tab.e[6]  = { gatW + 65536,   917504,  256,  256,  896,  1 };
    tab.e[7]  = { dgatW,          983040,  256,  256,  960,  1 };
    tab.e[8]  = { dgatW + 65536,  1048576, 256,  256,  1024, 1 };
    tab.e[9]  = { clsWq,          1114112, 256,  256,  1088, 0 };
    tab.e[10] = { clsWk,          1179648, 256,  256,  1152, 0 };
    tab.e[11] = { clsWq + 65536,  1245184, 256,  256,  1216, 0 };
    tab.e[12] = { clsWk + 65536,  1310720, 256,  256,  1280, 0 };

    // prep + graph + embeddings (+fused LN for track rows)
    k_prep<<<1344, 256, 0, stream>>>(tab, wbuf);
    k_wcomb<<<32, 256, 0, stream>>>(wbuf);
    k_nodes<<<64, 256, 0, stream>>>(tracks, dets, tmarks, dmarks, nodes, maxd_all);
    k_adjmask<<<768, 256, 0, stream>>>(nodes, adjm_main, adjm_det);
    k_featgemm<<<1152, 256, 0, stream>>>(tracks, dets, W1, b1, W2T, b2,
        hln, emb_r0_f, feat0_f, feat0_b, demb_b);

    // encoder (only r=0 row needed downstream of attention)
    k_kvq<<<2176, 256, 0, stream>>>(hln, WqkvT, kv_b, q_b);
    k_attn<<<8192, 256, 0, stream>>>(q_b, kv_b, o0_b);
    k_addres_ln<<<128, 256, 0, stream>>>(o0_b, WoT, emb_r0_f, x20, h2_b);
    k_gemm128_bf16<<<dim3(8, 64, 1), 256, 0, stream>>>(h2_b, 256, eff1T, 256, f1_b, 1024, 256, 1);
    k_gemm_pred<<<dim3(4, 128, 1), 256, 0, stream>>>(f1_b, 1024, eff2T, 1024, emb_r0_f, x20, feat0_f, feat0_b, 1024);

    // GAT layer 1 (main + det combined)
    k_gemmT_src<<<1536, 256, 0, stream>>>(
        gatW0T, feat0_b, hgT_m, gatA, (float*)src4, (float*)dst4, maxd_all,
        dgatW0T, demb_b, hgT_d, dgatA, (float*)srcd4, (float*)dstd4, maxd_all + 128);
    k_gatagg5<<<768, 256, 0, stream>>>(
        hgT_m, adjm_main, src4, maxd_all, dst4, feat0_f, xga_m,
        hgT_d, adjm_det, srcd4, maxd_all + 128, dstd4, feat0_f + 131072, xga_d);
    // GAT layer 2 (main + det combined)
    k_gemmT_src<<<1536, 256, 0, stream>>>(
        gatW1T, xga_m, hgT_m, gatA + 512, (float*)src4, (float*)dst4, maxd_all + 64,
        dgatW1T, xga_d, hgT_d, dgatA + 512, (float*)srcd4, (float*)dstd4, maxd_all + 192);
    k_gatagg5<<<768, 256, 0, stream>>>(
        hgT_m, adjm_main, src4, maxd_all + 64, dst4, feat0_f, xgb_m,
        hgT_d, adjm_det, srcd4, maxd_all + 192, dstd4, feat0_f + 131072, xgb_d);

    // y = x @ Wc, then logits = y @ x^T (main + det combined)
    k_y<<<1536, 256, 0, stream>>>(xgb_m, WcT0, y_m, xgb_d, WcT1, y_d);
    k_logits<<<1280, 256, 0, stream>>>(y_m, xgb_m, y_d, xgb_d, adjm_main, adjm_det,
        out, out + 20971520L);
}